// Round 1
// baseline (1013.816 us; speedup 1.0000x reference)
//
#include <hip/hip_runtime.h>
#include <math.h>

#define NPIX 3136   // 56*56
#define CCH  224
#define SCALING 0.17677669529663687f  // 32^-0.5

// ---------------- helpers ----------------
__device__ __forceinline__ void blockReduce2(float& a, float& b, float* scratch) {
  // block of 256 threads = 4 waves of 64
  #pragma unroll
  for (int off = 32; off > 0; off >>= 1) {
    a += __shfl_down(a, off);
    b += __shfl_down(b, off);
  }
  int wid = threadIdx.x >> 6, lane = threadIdx.x & 63;
  if (lane == 0) { scratch[wid * 2] = a; scratch[wid * 2 + 1] = b; }
  __syncthreads();
  if (threadIdx.x == 0) {
    float sa = 0.f, sb = 0.f;
    #pragma unroll
    for (int i = 0; i < 4; ++i) { sa += scratch[2 * i]; sb += scratch[2 * i + 1]; }
    scratch[0] = sa; scratch[1] = sb;
  }
  __syncthreads();
  a = scratch[0]; b = scratch[1];
}

// ---------------- lam = clip(exp(lq1.lk1)-exp(lq2.lk2),0,1)+lambda_init ----------------
__global__ void lam_kernel(const float* __restrict__ lq1, const float* __restrict__ lk1,
                           const float* __restrict__ lq2, const float* __restrict__ lk2,
                           const float* __restrict__ lambda_init, float* __restrict__ lam) {
  int t = threadIdx.x;  // 64 threads
  float p1 = (t < 32) ? lq1[t] * lk1[t] : 0.f;
  float p2 = (t < 32) ? lq2[t] * lk2[t] : 0.f;
  #pragma unroll
  for (int off = 16; off > 0; off >>= 1) {
    p1 += __shfl_down(p1, off);
    p2 += __shfl_down(p2, off);
  }
  if (t == 0) {
    float d = expf(p1) - expf(p2);
    d = fminf(fmaxf(d, 0.f), 1.f);
    lam[0] = d + lambda_init[0];
  }
}

// ---------------- prep: gating + per-channel instance norm ----------------
__global__ __launch_bounds__(256) void prep_kernel(const float* __restrict__ D,
                                                   const float* __restrict__ gn_w,
                                                   const float* __restrict__ gn_b,
                                                   float* __restrict__ senh) {
  __shared__ float img[NPIX];
  __shared__ float xh[56];
  __shared__ float xw[56];
  __shared__ float scratch[8];
  int bc = blockIdx.x;          // b*224 + c
  int c = bc % CCH;
  const float* src = D + (size_t)bc * NPIX;
  float4* img4 = (float4*)img;
  const float4* src4 = (const float4*)src;
  for (int i = threadIdx.x; i < NPIX / 4; i += 256) img4[i] = src4[i];
  __syncthreads();
  if (threadIdx.x < 56) {
    int h = threadIdx.x;
    float s = 0.f;
    #pragma unroll 8
    for (int w = 0; w < 56; ++w) s += img[h * 56 + w];
    xh[h] = s * (1.f / 56.f);
  } else if (threadIdx.x >= 64 && threadIdx.x < 120) {
    int w = threadIdx.x - 64;
    float s = 0.f;
    #pragma unroll 8
    for (int h = 0; h < 56; ++h) s += img[h * 56 + w];
    xw[w] = s * (1.f / 56.f);
  }
  __syncthreads();
  float sum = 0.f, ssq = 0.f;
  for (int i = threadIdx.x; i < NPIX; i += 256) {
    int y = i / 56, x = i - y * 56;
    float d = img[i];
    float t = xh[y] + xw[x];
    float sg = 1.f / (1.f + __expf(-t));
    float g = d * sg;
    img[i] = g;
    sum += g;
    ssq += g * g;
  }
  blockReduce2(sum, ssq, scratch);
  float mu = sum * (1.f / (float)NPIX);
  float var = ssq * (1.f / (float)NPIX) - mu * mu;   // biased, matches jnp.var
  float rstd = rsqrtf(var + 1e-5f);
  float a = gn_w[c] * rstd;
  float bb = gn_b[c] - mu * a;
  float* dst = senh + (size_t)bc * NPIX;
  for (int i = threadIdx.x; i < NPIX; i += 256) dst[i] = fmaf(img[i], a, bb);
}

// ---------------- conv1x1 as GEMM: Y[M,N] = A[M,224] * X[224,N] + bias ----------------
// mode 0: plain. mode 1 (Q): row r scaled by (r<224 ? s : -lam*s), bias folded before scale.
__global__ __launch_bounds__(256) void gemm_kernel(const float* __restrict__ A,
                                                   const float* __restrict__ X,
                                                   const float* __restrict__ bias,
                                                   float* __restrict__ Y, int M, int mode,
                                                   const float* __restrict__ lamp) {
  __shared__ float As[16][64];
  __shared__ float Bs[16][64];
  int b = blockIdx.z;
  const float* Xb = X + (size_t)b * CCH * NPIX;
  float* Yb = Y + (size_t)b * M * NPIX;
  int r0 = blockIdx.y * 64, n0 = blockIdx.x * 64;
  int tid = threadIdx.x;
  int tx = tid & 15, ty = tid >> 4;
  float acc[4][4] = {{0.f}};
  int ar = r0 + (tid >> 2);
  int ak = (tid & 3) * 4;
  int xk = tid >> 4;
  int xn = n0 + (tid & 15) * 4;
  for (int k0 = 0; k0 < CCH; k0 += 16) {
    float4 av = make_float4(0.f, 0.f, 0.f, 0.f);
    if (ar < M) av = *(const float4*)(A + (size_t)ar * CCH + k0 + ak);
    float4 xv = *(const float4*)(Xb + (size_t)(k0 + xk) * NPIX + xn);
    As[ak + 0][tid >> 2] = av.x;
    As[ak + 1][tid >> 2] = av.y;
    As[ak + 2][tid >> 2] = av.z;
    As[ak + 3][tid >> 2] = av.w;
    *(float4*)&Bs[xk][(tid & 15) * 4] = xv;
    __syncthreads();
    #pragma unroll
    for (int kk = 0; kk < 16; ++kk) {
      const float4 a4 = *(const float4*)&As[kk][ty * 4];
      const float4 b4 = *(const float4*)&Bs[kk][tx * 4];
      acc[0][0] = fmaf(a4.x, b4.x, acc[0][0]);
      acc[0][1] = fmaf(a4.x, b4.y, acc[0][1]);
      acc[0][2] = fmaf(a4.x, b4.z, acc[0][2]);
      acc[0][3] = fmaf(a4.x, b4.w, acc[0][3]);
      acc[1][0] = fmaf(a4.y, b4.x, acc[1][0]);
      acc[1][1] = fmaf(a4.y, b4.y, acc[1][1]);
      acc[1][2] = fmaf(a4.y, b4.z, acc[1][2]);
      acc[1][3] = fmaf(a4.y, b4.w, acc[1][3]);
      acc[2][0] = fmaf(a4.z, b4.x, acc[2][0]);
      acc[2][1] = fmaf(a4.z, b4.y, acc[2][1]);
      acc[2][2] = fmaf(a4.z, b4.z, acc[2][2]);
      acc[2][3] = fmaf(a4.z, b4.w, acc[2][3]);
      acc[3][0] = fmaf(a4.w, b4.x, acc[3][0]);
      acc[3][1] = fmaf(a4.w, b4.y, acc[3][1]);
      acc[3][2] = fmaf(a4.w, b4.z, acc[3][2]);
      acc[3][3] = fmaf(a4.w, b4.w, acc[3][3]);
    }
    __syncthreads();
  }
  float lam = (mode == 1) ? lamp[0] : 0.f;
  #pragma unroll
  for (int i = 0; i < 4; ++i) {
    int r = r0 + ty * 4 + i;
    if (r >= M) continue;
    float scale = 1.f;
    if (mode == 1) scale = (r < CCH) ? SCALING : (-lam * SCALING);
    float bi = bias[r];
    float4 o;
    o.x = (acc[i][0] + bi) * scale;
    o.y = (acc[i][1] + bi) * scale;
    o.z = (acc[i][2] + bi) * scale;
    o.w = (acc[i][3] + bi) * scale;
    *(float4*)(Yb + (size_t)r * NPIX + n0 + tx * 4) = o;
  }
}

// ---------------- flash attention (fp32) ----------------
// Qc already holds scaling / -lam*scaling folded in. logits = Qc0.K0 + Qc1.K1 (64-dim dot).
// Block: 64 queries, 4-way key split per query (lanes 4k..4k+3 share a query).
__global__ __launch_bounds__(256) void attn_kernel(const float* __restrict__ Qc,
                                                   const float* __restrict__ K,
                                                   const float* __restrict__ V,
                                                   float* __restrict__ out) {
  __shared__ float Kt[64][64];
  __shared__ float Vt[32][64];
  int b = blockIdx.z, h = blockIdx.y, qt = blockIdx.x;
  int tid = threadIdx.x;
  int ks = tid & 3, tq = tid >> 2;
  int ks16 = ks * 16;
  int nq = qt * 64 + tq;
  const float* Qb = Qc + (size_t)b * 448 * NPIX;
  const float* Kb = K + (size_t)b * 448 * NPIX;
  const float* Vb = V + (size_t)b * CCH * NPIX;

  float q[64];
  #pragma unroll
  for (int d = 0; d < 32; ++d) {
    q[d] = Qb[(size_t)(h * 32 + d) * NPIX + nq];
    q[32 + d] = Qb[(size_t)(CCH + h * 32 + d) * NPIX + nq];
  }

  float mrun = -INFINITY, l = 0.f;
  float acc[32];
  #pragma unroll
  for (int d = 0; d < 32; ++d) acc[d] = 0.f;

  // staging assignments
  int sd = tid >> 2;               // 0..63 (dim)
  int sj = (tid & 3) * 16;         // key offset
  int srow = (sd < 32) ? (h * 32 + sd) : (CCH + h * 32 + sd - 32);
  const float* ksrc = Kb + (size_t)srow * NPIX;
  int vd = (tid >> 2) & 31;
  const float* vsrc = Vb + (size_t)(h * 32 + vd) * NPIX;

  for (int kc = 0; kc < 49; ++kc) {
    int m0 = kc * 64;
    {
      const float4* s4 = (const float4*)(ksrc + m0 + sj);
      float4 v0 = s4[0], v1 = s4[1], v2 = s4[2], v3 = s4[3];
      float4* dst = (float4*)&Kt[sd][sj];
      dst[0] = v0; dst[1] = v1; dst[2] = v2; dst[3] = v3;
    }
    if (tid < 128) {
      const float4* s4 = (const float4*)(vsrc + m0 + sj);
      float4 v0 = s4[0], v1 = s4[1], v2 = s4[2], v3 = s4[3];
      float4* dst = (float4*)&Vt[vd][sj];
      dst[0] = v0; dst[1] = v1; dst[2] = v2; dst[3] = v3;
    }
    __syncthreads();

    float s[16];
    #pragma unroll
    for (int i = 0; i < 16; ++i) s[i] = 0.f;
    #pragma unroll
    for (int d = 0; d < 64; ++d) {
      const float qd = q[d];
      const float4 k0 = *(const float4*)&Kt[d][ks16];
      const float4 k1 = *(const float4*)&Kt[d][ks16 + 4];
      const float4 k2 = *(const float4*)&Kt[d][ks16 + 8];
      const float4 k3 = *(const float4*)&Kt[d][ks16 + 12];
      s[0] = fmaf(qd, k0.x, s[0]);  s[1] = fmaf(qd, k0.y, s[1]);
      s[2] = fmaf(qd, k0.z, s[2]);  s[3] = fmaf(qd, k0.w, s[3]);
      s[4] = fmaf(qd, k1.x, s[4]);  s[5] = fmaf(qd, k1.y, s[5]);
      s[6] = fmaf(qd, k1.z, s[6]);  s[7] = fmaf(qd, k1.w, s[7]);
      s[8] = fmaf(qd, k2.x, s[8]);  s[9] = fmaf(qd, k2.y, s[9]);
      s[10] = fmaf(qd, k2.z, s[10]); s[11] = fmaf(qd, k2.w, s[11]);
      s[12] = fmaf(qd, k3.x, s[12]); s[13] = fmaf(qd, k3.y, s[13]);
      s[14] = fmaf(qd, k3.z, s[14]); s[15] = fmaf(qd, k3.w, s[15]);
    }

    float smax = s[0];
    #pragma unroll
    for (int i = 1; i < 16; ++i) smax = fmaxf(smax, s[i]);
    float mnew = fmaxf(mrun, smax);
    float corr = __expf(mrun - mnew);
    l *= corr;
    #pragma unroll
    for (int i = 0; i < 16; ++i) {
      s[i] = __expf(s[i] - mnew);
      l += s[i];
    }
    #pragma unroll
    for (int d = 0; d < 32; ++d) acc[d] *= corr;
    #pragma unroll
    for (int d = 0; d < 32; ++d) {
      const float4 v0 = *(const float4*)&Vt[d][ks16];
      const float4 v1 = *(const float4*)&Vt[d][ks16 + 4];
      const float4 v2 = *(const float4*)&Vt[d][ks16 + 8];
      const float4 v3 = *(const float4*)&Vt[d][ks16 + 12];
      float a = acc[d];
      a = fmaf(s[0], v0.x, a);  a = fmaf(s[1], v0.y, a);
      a = fmaf(s[2], v0.z, a);  a = fmaf(s[3], v0.w, a);
      a = fmaf(s[4], v1.x, a);  a = fmaf(s[5], v1.y, a);
      a = fmaf(s[6], v1.z, a);  a = fmaf(s[7], v1.w, a);
      a = fmaf(s[8], v2.x, a);  a = fmaf(s[9], v2.y, a);
      a = fmaf(s[10], v2.z, a); a = fmaf(s[11], v2.w, a);
      a = fmaf(s[12], v3.x, a); a = fmaf(s[13], v3.y, a);
      a = fmaf(s[14], v3.w == v3.w ? v3.z : v3.z, a); // v3.z
      a = fmaf(s[15], v3.w, a);
      acc[d] = a;
    }
    mrun = mnew;
    __syncthreads();
  }

  // merge the 4 key-splits (adjacent lanes) via shfl
  #pragma unroll
  for (int off = 1; off <= 2; off <<= 1) {
    float mo = __shfl_xor(mrun, off);
    float lo = __shfl_xor(l, off);
    float mnew = fmaxf(mrun, mo);
    float fa = __expf(mrun - mnew);
    float fb = __expf(mo - mnew);
    l = l * fa + lo * fb;
    #pragma unroll
    for (int d = 0; d < 32; ++d) {
      float ao = __shfl_xor(acc[d], off);
      acc[d] = acc[d] * fa + ao * fb;
    }
    mrun = mnew;
  }
  if (ks == 0) {
    float inv = 1.f / l;
    float* ob = out + ((size_t)b * CCH + h * 32) * NPIX + nq;
    #pragma unroll
    for (int d = 0; d < 32; ++d) ob[(size_t)d * NPIX] = acc[d] * inv;
  }
}

// ---------------- channel means of attention output -> wx = wo * sigmoid(mean) ----------------
__global__ __launch_bounds__(256) void wx_kernel(const float* __restrict__ out,
                                                 const float* __restrict__ wo,
                                                 float* __restrict__ wx) {
  __shared__ float scratch[8];
  int bc = blockIdx.x;
  int c = bc % CCH;
  const float* src = out + (size_t)bc * NPIX;
  float s = 0.f, dummy = 0.f;
  for (int i = threadIdx.x; i < NPIX; i += 256) s += src[i];
  blockReduce2(s, dummy, scratch);
  if (threadIdx.x == 0) {
    float mean = s * (1.f / (float)NPIX);
    float x1 = 1.f / (1.f + expf(-mean));
    wx[bc] = wo[c] * x1;
  }
}

// ---------------- weff[b,cp,k] = sum_c wx[b,c]*w3[c,cp,k]; beff[b] = sum_c wx*b3 + bo ----------------
__global__ __launch_bounds__(256) void weff_kernel(const float* __restrict__ wx,
                                                   const float* __restrict__ w3,
                                                   const float* __restrict__ b3,
                                                   const float* __restrict__ bo,
                                                   float* __restrict__ weff,
                                                   float* __restrict__ beff) {
  int k = blockIdx.x;   // 0..8
  int b = blockIdx.y;
  int cp = threadIdx.x;
  const float* wxb = wx + b * CCH;
  if (cp < CCH) {
    float acc = 0.f;
    for (int c = 0; c < CCH; ++c)
      acc = fmaf(wxb[c], w3[((size_t)c * CCH + cp) * 9 + k], acc);
    weff[(size_t)b * (CCH * 9) + cp * 9 + k] = acc;
  }
  if (k == 0) {
    __shared__ float scratch[8];
    float p = (cp < CCH) ? wxb[cp] * b3[cp] : 0.f;
    float dummy = 0.f;
    blockReduce2(p, dummy, scratch);
    if (threadIdx.x == 0) beff[b] = p + bo[0];
  }
}

// ---------------- 3x3 conv with the collapsed weights, accumulated atomically ----------------
__global__ __launch_bounds__(256) void conv_kernel(const float* __restrict__ out,
                                                   const float* __restrict__ weff,
                                                   float* __restrict__ accum) {
  __shared__ float img[NPIX];
  int b = blockIdx.y;
  int cg = blockIdx.x;  // 0..55, 4 channels each
  float racc[13];
  #pragma unroll
  for (int r = 0; r < 13; ++r) racc[r] = 0.f;
  const float* wef = weff + (size_t)b * (CCH * 9);
  for (int ci = 0; ci < 4; ++ci) {
    int cp = cg * 4 + ci;
    const float* src = out + ((size_t)b * CCH + cp) * NPIX;
    __syncthreads();
    float4* img4 = (float4*)img;
    const float4* src4 = (const float4*)src;
    for (int i = threadIdx.x; i < NPIX / 4; i += 256) img4[i] = src4[i];
    __syncthreads();
    float w[9];
    #pragma unroll
    for (int k = 0; k < 9; ++k) w[k] = wef[cp * 9 + k];
    #pragma unroll
    for (int r = 0; r < 13; ++r) {
      int i = threadIdx.x + r * 256;
      if (i < NPIX) {
        int y = i / 56, x = i - y * 56;
        float a = 0.f;
        #pragma unroll
        for (int ky = 0; ky < 3; ++ky) {
          int yy = y + ky - 1;
          if (yy < 0 || yy >= 56) continue;
          #pragma unroll
          for (int kx = 0; kx < 3; ++kx) {
            int xx = x + kx - 1;
            if (xx < 0 || xx >= 56) continue;
            a = fmaf(w[ky * 3 + kx], img[yy * 56 + xx], a);
          }
        }
        racc[r] += a;
      }
    }
  }
  #pragma unroll
  for (int r = 0; r < 13; ++r) {
    int i = threadIdx.x + r * 256;
    if (i < NPIX) atomicAdd(&accum[(size_t)b * NPIX + i], racc[r]);
  }
}

// ---------------- finalize: sigmoid(accum + beff) ----------------
__global__ void fin_kernel(const float* __restrict__ accum, const float* __restrict__ beff,
                           float* __restrict__ dout) {
  int i = blockIdx.x * 256 + threadIdx.x;
  if (i < 2 * NPIX) {
    int b = i / NPIX;
    float v = accum[i] + beff[b];
    dout[i] = 1.f / (1.f + expf(-v));
  }
}

extern "C" void kernel_launch(void* const* d_in, const int* in_sizes, int n_in,
                              void* d_out, int out_size, void* d_ws, size_t ws_size,
                              hipStream_t stream) {
  (void)in_sizes; (void)n_in; (void)out_size; (void)ws_size;
  const float* D = (const float*)d_in[0];
  const float* wq = (const float*)d_in[1];
  const float* bq = (const float*)d_in[2];
  const float* wk = (const float*)d_in[3];
  const float* bk = (const float*)d_in[4];
  const float* wv = (const float*)d_in[5];
  const float* bv = (const float*)d_in[6];
  const float* gn_w = (const float*)d_in[7];
  const float* gn_b = (const float*)d_in[8];
  const float* lambda_init = (const float*)d_in[9];
  const float* lq1 = (const float*)d_in[10];
  const float* lk1 = (const float*)d_in[11];
  const float* lq2 = (const float*)d_in[12];
  const float* lk2 = (const float*)d_in[13];
  const float* w3 = (const float*)d_in[14];
  const float* b3 = (const float*)d_in[15];
  const float* wo = (const float*)d_in[16];
  const float* bo = (const float*)d_in[17];

  float* ws = (float*)d_ws;
  const size_t SZ_CHW = (size_t)2 * CCH * NPIX;   // 1,404,928
  const size_t SZ_QK = (size_t)2 * 448 * NPIX;    // 2,809,856
  float* senh = ws;
  float* Qb = senh + SZ_CHW;
  float* Kb = Qb + SZ_QK;
  float* Vb = Kb + SZ_QK;
  float* attno = Vb + SZ_CHW;
  float* wx = attno + SZ_CHW;
  float* weff = wx + 2 * CCH;
  float* beff = weff + 2 * CCH * 9;
  float* lam = beff + 2;
  float* accum = lam + 1;

  hipMemsetAsync(accum, 0, 2 * NPIX * sizeof(float), stream);
  lam_kernel<<<1, 64, 0, stream>>>(lq1, lk1, lq2, lk2, lambda_init, lam);
  prep_kernel<<<448, 256, 0, stream>>>(D, gn_w, gn_b, senh);
  gemm_kernel<<<dim3(49, 7, 2), 256, 0, stream>>>(wq, senh, bq, Qb, 448, 1, lam);
  gemm_kernel<<<dim3(49, 7, 2), 256, 0, stream>>>(wk, D, bk, Kb, 448, 0, nullptr);
  gemm_kernel<<<dim3(49, 4, 2), 256, 0, stream>>>(wv, D, bv, Vb, 224, 0, nullptr);
  attn_kernel<<<dim3(49, 7, 2), 256, 0, stream>>>(Qb, Kb, Vb, attno);
  wx_kernel<<<448, 256, 0, stream>>>(attno, wo, wx);
  weff_kernel<<<dim3(9, 2), 256, 0, stream>>>(wx, w3, b3, bo, weff, beff);
  conv_kernel<<<dim3(56, 2), 256, 0, stream>>>(attno, weff, accum);
  fin_kernel<<<25, 256, 0, stream>>>(accum, beff, (float*)d_out);
}

// Round 3
// 345.428 us; speedup vs baseline: 2.9350x; 2.9350x over previous
//
#include <hip/hip_runtime.h>
#include <math.h>

#define NPIX 3136   // 56*56
#define CCH  224
#define SCALING 0.17677669529663687f  // 32^-0.5

typedef _Float16 half8_t __attribute__((ext_vector_type(8)));
typedef _Float16 half4_t __attribute__((ext_vector_type(4)));
typedef _Float16 half2_t __attribute__((ext_vector_type(2)));
typedef float floatx4 __attribute__((ext_vector_type(4)));

// ---------------- helpers ----------------
__device__ __forceinline__ void blockReduce2(float& a, float& b, float* scratch) {
  #pragma unroll
  for (int off = 32; off > 0; off >>= 1) {
    a += __shfl_down(a, off);
    b += __shfl_down(b, off);
  }
  int wid = threadIdx.x >> 6, lane = threadIdx.x & 63;
  if (lane == 0) { scratch[wid * 2] = a; scratch[wid * 2 + 1] = b; }
  __syncthreads();
  if (threadIdx.x == 0) {
    float sa = 0.f, sb = 0.f;
    #pragma unroll
    for (int i = 0; i < 4; ++i) { sa += scratch[2 * i]; sb += scratch[2 * i + 1]; }
    scratch[0] = sa; scratch[1] = sb;
  }
  __syncthreads();
  a = scratch[0]; b = scratch[1];
}

// ---------------- lam ----------------
__global__ void lam_kernel(const float* __restrict__ lq1, const float* __restrict__ lk1,
                           const float* __restrict__ lq2, const float* __restrict__ lk2,
                           const float* __restrict__ lambda_init, float* __restrict__ lam) {
  int t = threadIdx.x;
  float p1 = (t < 32) ? lq1[t] * lk1[t] : 0.f;
  float p2 = (t < 32) ? lq2[t] * lk2[t] : 0.f;
  #pragma unroll
  for (int off = 16; off > 0; off >>= 1) {
    p1 += __shfl_down(p1, off);
    p2 += __shfl_down(p2, off);
  }
  if (t == 0) {
    float d = expf(p1) - expf(p2);
    d = fminf(fmaxf(d, 0.f), 1.f);
    lam[0] = d + lambda_init[0];
  }
}

// ---------------- prep: gating + per-channel instance norm ----------------
__global__ __launch_bounds__(256) void prep_kernel(const float* __restrict__ D,
                                                   const float* __restrict__ gn_w,
                                                   const float* __restrict__ gn_b,
                                                   float* __restrict__ senh) {
  __shared__ float img[NPIX];
  __shared__ float xh[56];
  __shared__ float xw[56];
  __shared__ float scratch[8];
  int bc = blockIdx.x;
  int c = bc % CCH;
  const float* src = D + (size_t)bc * NPIX;
  float4* img4 = (float4*)img;
  const float4* src4 = (const float4*)src;
  for (int i = threadIdx.x; i < NPIX / 4; i += 256) img4[i] = src4[i];
  __syncthreads();
  if (threadIdx.x < 56) {
    int h = threadIdx.x;
    float s = 0.f;
    #pragma unroll 8
    for (int w = 0; w < 56; ++w) s += img[h * 56 + w];
    xh[h] = s * (1.f / 56.f);
  } else if (threadIdx.x >= 64 && threadIdx.x < 120) {
    int w = threadIdx.x - 64;
    float s = 0.f;
    #pragma unroll 8
    for (int h = 0; h < 56; ++h) s += img[h * 56 + w];
    xw[w] = s * (1.f / 56.f);
  }
  __syncthreads();
  float sum = 0.f, ssq = 0.f;
  for (int i = threadIdx.x; i < NPIX; i += 256) {
    int y = i / 56, x = i - y * 56;
    float d = img[i];
    float t = xh[y] + xw[x];
    float sg = 1.f / (1.f + __expf(-t));
    float g = d * sg;
    img[i] = g;
    sum += g;
    ssq += g * g;
  }
  blockReduce2(sum, ssq, scratch);
  float mu = sum * (1.f / (float)NPIX);
  float var = ssq * (1.f / (float)NPIX) - mu * mu;
  float rstd = rsqrtf(var + 1e-5f);
  float a = gn_w[c] * rstd;
  float bb = gn_b[c] - mu * a;
  float* dst = senh + (size_t)bc * NPIX;
  for (int i = threadIdx.x; i < NPIX; i += 256) dst[i] = fmaf(img[i], a, bb);
}

// ---------------- conv1x1 as fp32 GEMM ----------------
__global__ __launch_bounds__(256) void gemm_kernel(const float* __restrict__ A,
                                                   const float* __restrict__ X,
                                                   const float* __restrict__ bias,
                                                   float* __restrict__ Y, int M, int mode,
                                                   const float* __restrict__ lamp) {
  __shared__ float As[16][64];
  __shared__ float Bs[16][64];
  int b = blockIdx.z;
  const float* Xb = X + (size_t)b * CCH * NPIX;
  float* Yb = Y + (size_t)b * M * NPIX;
  int r0 = blockIdx.y * 64, n0 = blockIdx.x * 64;
  int tid = threadIdx.x;
  int tx = tid & 15, ty = tid >> 4;
  float acc[4][4] = {{0.f}};
  int ar = r0 + (tid >> 2);
  int ak = (tid & 3) * 4;
  int xk = tid >> 4;
  int xn = n0 + (tid & 15) * 4;
  for (int k0 = 0; k0 < CCH; k0 += 16) {
    float4 av = make_float4(0.f, 0.f, 0.f, 0.f);
    if (ar < M) av = *(const float4*)(A + (size_t)ar * CCH + k0 + ak);
    float4 xv = *(const float4*)(Xb + (size_t)(k0 + xk) * NPIX + xn);
    As[ak + 0][tid >> 2] = av.x;
    As[ak + 1][tid >> 2] = av.y;
    As[ak + 2][tid >> 2] = av.z;
    As[ak + 3][tid >> 2] = av.w;
    *(float4*)&Bs[xk][(tid & 15) * 4] = xv;
    __syncthreads();
    #pragma unroll
    for (int kk = 0; kk < 16; ++kk) {
      const float4 a4 = *(const float4*)&As[kk][ty * 4];
      const float4 b4 = *(const float4*)&Bs[kk][tx * 4];
      acc[0][0] = fmaf(a4.x, b4.x, acc[0][0]);
      acc[0][1] = fmaf(a4.x, b4.y, acc[0][1]);
      acc[0][2] = fmaf(a4.x, b4.z, acc[0][2]);
      acc[0][3] = fmaf(a4.x, b4.w, acc[0][3]);
      acc[1][0] = fmaf(a4.y, b4.x, acc[1][0]);
      acc[1][1] = fmaf(a4.y, b4.y, acc[1][1]);
      acc[1][2] = fmaf(a4.y, b4.z, acc[1][2]);
      acc[1][3] = fmaf(a4.y, b4.w, acc[1][3]);
      acc[2][0] = fmaf(a4.z, b4.x, acc[2][0]);
      acc[2][1] = fmaf(a4.z, b4.y, acc[2][1]);
      acc[2][2] = fmaf(a4.z, b4.z, acc[2][2]);
      acc[2][3] = fmaf(a4.z, b4.w, acc[2][3]);
      acc[3][0] = fmaf(a4.w, b4.x, acc[3][0]);
      acc[3][1] = fmaf(a4.w, b4.y, acc[3][1]);
      acc[3][2] = fmaf(a4.w, b4.z, acc[3][2]);
      acc[3][3] = fmaf(a4.w, b4.w, acc[3][3]);
    }
    __syncthreads();
  }
  float lam = (mode == 1) ? lamp[0] : 0.f;
  #pragma unroll
  for (int i = 0; i < 4; ++i) {
    int r = r0 + ty * 4 + i;
    if (r >= M) continue;
    float scale = 1.f;
    if (mode == 1) scale = (r < CCH) ? SCALING : (-lam * SCALING);
    float bi = bias[r];
    float4 o;
    o.x = (acc[i][0] + bi) * scale;
    o.y = (acc[i][1] + bi) * scale;
    o.z = (acc[i][2] + bi) * scale;
    o.w = (acc[i][3] + bi) * scale;
    *(float4*)(Yb + (size_t)r * NPIX + n0 + tx * 4) = o;
  }
}

// ---------------- MFMA flash attention (f16 in, fp32 accum) ----------------
// Qc holds scaling / -lam*scaling folded in. logits = 64-dim concat dot.
// Block: 64 queries (4 waves x 16q), 49 key-tiles of 64.
// S^T = mfma(K_frag, Q_frag): lane: q = lane&15, key = 16t + 4g + reg.
// PV:  O^T = mfma(V_frag, P_frag) with P routed via per-wave LDS tile.
__global__ __launch_bounds__(256) void attn_kernel(const float* __restrict__ Qc,
                                                   const float* __restrict__ K,
                                                   const float* __restrict__ V,
                                                   float* __restrict__ out) {
  __shared__ _Float16 K_lds[64][72];   // [key][dim], pad->72 halfs (144B rows)
  __shared__ _Float16 V_lds[32][72];   // [dim][key]
  __shared__ _Float16 P_lds[64][72];   // [w*16+q][key] per-wave private rows

  int b = blockIdx.z, h = blockIdx.y, qt = blockIdx.x;
  int tid = threadIdx.x;
  int w = tid >> 6;
  int lane = tid & 63;
  int q = lane & 15;
  int g = lane >> 4;

  const float* Qb = Qc + (size_t)b * 448 * NPIX;
  const float* Kb = K + (size_t)b * 448 * NPIX;
  const float* Vb = V + (size_t)b * CCH * NPIX;

  int nq = qt * 64 + w * 16 + q;

  // Q fragments: B[k=d][j=q], k-map d = 32c + 8g + e (consistent with A side)
  half8_t qv[2];
  #pragma unroll
  for (int c = 0; c < 2; ++c) {
    #pragma unroll
    for (int e = 0; e < 8; ++e) {
      int dl = g * 8 + e;
      int ch = (c == 0) ? (h * 32 + dl) : (CCH + h * 32 + dl);
      qv[c][e] = (_Float16)Qb[(size_t)ch * NPIX + nq];
    }
  }

  floatx4 oacc[2];
  #pragma unroll
  for (int dt = 0; dt < 2; ++dt)
    #pragma unroll
    for (int r = 0; r < 4; ++r) oacc[dt][r] = 0.f;
  float mrun = -INFINITY, lrun = 0.f;

  // ---- staging assignments ----
  // K: dim-pair scheme — thread owns dims (2sd, 2sd+1) x 8 keys.
  //    half2 LDS writes: bank = (sd + 36*(8kq+j)) % 32; 36*8 % 32 == 0 so the
  //    only aliasing is the free 2-way (kq groups). No 8-way conflicts.
  int sd = tid & 31;                    // dim pair index 0..31
  int kq = tid >> 5;                    // key-octet 0..7
  int dA = 2 * sd, dB = 2 * sd + 1;
  int chA = (dA < 32) ? (h * 32 + dA) : (CCH - 32 + h * 32 + dA);
  int chB = (dB < 32) ? (h * 32 + dB) : (CCH - 32 + h * 32 + dB);
  const float* ksrcA = Kb + (size_t)chA * NPIX + kq * 8;
  const float* ksrcB = Kb + (size_t)chB * NPIX + kq * 8;
  // V: straight [dim][key], half8 writes
  int vd = tid >> 3;                    // 0..31
  int vk0 = (tid & 7) << 3;             // key offset, 8 apart
  const float* vsrc = Vb + (size_t)(h * 32 + vd) * NPIX + vk0;

  for (int kc = 0; kc < 49; ++kc) {
    int m0 = kc * 64;
    // ---- stage K (transpose to [key][dim]) ----
    {
      const float4* a4 = (const float4*)(ksrcA + m0);
      const float4* b4 = (const float4*)(ksrcB + m0);
      float4 a0 = a4[0], a1 = a4[1];
      float4 b0 = b4[0], b1 = b4[1];
      float av[8] = {a0.x, a0.y, a0.z, a0.w, a1.x, a1.y, a1.z, a1.w};
      float bv[8] = {b0.x, b0.y, b0.z, b0.w, b1.x, b1.y, b1.z, b1.w};
      #pragma unroll
      for (int j = 0; j < 8; ++j) {
        half2_t hw;
        hw[0] = (_Float16)av[j];
        hw[1] = (_Float16)bv[j];
        *(half2_t*)&K_lds[kq * 8 + j][2 * sd] = hw;
      }
    }
    // ---- stage V (straight [dim][key]) ----
    {
      const float4* s4 = (const float4*)(vsrc + m0);
      float4 a0 = s4[0], a1 = s4[1];
      half8_t hv;
      hv[0] = (_Float16)a0.x; hv[1] = (_Float16)a0.y;
      hv[2] = (_Float16)a0.z; hv[3] = (_Float16)a0.w;
      hv[4] = (_Float16)a1.x; hv[5] = (_Float16)a1.y;
      hv[6] = (_Float16)a1.z; hv[7] = (_Float16)a1.w;
      *(half8_t*)&V_lds[vd][vk0] = hv;
    }
    __syncthreads();

    // ---- QK^T: S^T[key][q] ----
    floatx4 sacc[4];
    #pragma unroll
    for (int t = 0; t < 4; ++t)
      #pragma unroll
      for (int r = 0; r < 4; ++r) sacc[t][r] = 0.f;
    #pragma unroll
    for (int t = 0; t < 4; ++t) {
      #pragma unroll
      for (int c = 0; c < 2; ++c) {
        half8_t ka = *(const half8_t*)&K_lds[t * 16 + q][c * 32 + g * 8];
        sacc[t] = __builtin_amdgcn_mfma_f32_16x16x32_f16(ka, qv[c], sacc[t], 0, 0, 0);
      }
    }

    // ---- online softmax over this 64-key tile (per q = lane&15) ----
    float tmax = sacc[0][0];
    #pragma unroll
    for (int t = 0; t < 4; ++t)
      #pragma unroll
      for (int r = 0; r < 4; ++r) tmax = fmaxf(tmax, sacc[t][r]);
    tmax = fmaxf(tmax, __shfl_xor(tmax, 16));
    tmax = fmaxf(tmax, __shfl_xor(tmax, 32));
    float mnew = fmaxf(mrun, tmax);
    float corr = __expf(mrun - mnew);
    float lsum = 0.f;
    #pragma unroll
    for (int t = 0; t < 4; ++t)
      #pragma unroll
      for (int r = 0; r < 4; ++r) {
        float p = __expf(sacc[t][r] - mnew);
        sacc[t][r] = p;
        lsum += p;
      }
    lsum += __shfl_xor(lsum, 16);
    lsum += __shfl_xor(lsum, 32);
    lrun = lrun * corr + lsum;
    #pragma unroll
    for (int dt = 0; dt < 2; ++dt)
      #pragma unroll
      for (int r = 0; r < 4; ++r) oacc[dt][r] *= corr;
    mrun = mnew;

    // ---- P -> f16 -> per-wave LDS tile [q][key] ----
    #pragma unroll
    for (int t = 0; t < 4; ++t) {
      half4_t ph;
      ph[0] = (_Float16)sacc[t][0];
      ph[1] = (_Float16)sacc[t][1];
      ph[2] = (_Float16)sacc[t][2];
      ph[3] = (_Float16)sacc[t][3];
      *(half4_t*)&P_lds[w * 16 + q][t * 16 + g * 4] = ph;
    }

    // ---- PV: O^T[d][q] += V[d][m] * P[m][q] ----
    #pragma unroll
    for (int dt = 0; dt < 2; ++dt) {
      #pragma unroll
      for (int c = 0; c < 2; ++c) {
        half8_t va = *(const half8_t*)&V_lds[dt * 16 + q][c * 32 + g * 8];
        half8_t pb = *(const half8_t*)&P_lds[w * 16 + q][c * 32 + g * 8];
        oacc[dt] = __builtin_amdgcn_mfma_f32_16x16x32_f16(va, pb, oacc[dt], 0, 0, 0);
      }
    }
    __syncthreads();
  }

  // ---- finalize: normalize, stage to LDS (transpose), coalesced global write ----
  float* out_lds = (float*)&K_lds[0][0];   // 32*68*4 = 8704B <= 9216B
  float inv = 1.f / lrun;
  #pragma unroll
  for (int dt = 0; dt < 2; ++dt)
    #pragma unroll
    for (int r = 0; r < 4; ++r) {
      int d = dt * 16 + g * 4 + r;
      out_lds[d * 68 + w * 16 + q] = oacc[dt][r] * inv;
    }
  __syncthreads();
  {
    int d = tid >> 3;
    int i8 = (tid & 7) << 3;
    float4 u0 = *(float4*)&out_lds[d * 68 + i8];
    float4 u1 = *(float4*)&out_lds[d * 68 + i8 + 4];
    float* dst = out + ((size_t)b * CCH + h * 32 + d) * NPIX + qt * 64 + i8;
    *(float4*)dst = u0;
    *(float4*)(dst + 4) = u1;
  }
}

// ---------------- channel means -> wx = wo * sigmoid(mean) ----------------
__global__ __launch_bounds__(256) void wx_kernel(const float* __restrict__ out,
                                                 const float* __restrict__ wo,
                                                 float* __restrict__ wx) {
  __shared__ float scratch[8];
  int bc = blockIdx.x;
  int c = bc % CCH;
  const float* src = out + (size_t)bc * NPIX;
  float s = 0.f, dummy = 0.f;
  for (int i = threadIdx.x; i < NPIX; i += 256) s += src[i];
  blockReduce2(s, dummy, scratch);
  if (threadIdx.x == 0) {
    float mean = s * (1.f / (float)NPIX);
    float x1 = 1.f / (1.f + expf(-mean));
    wx[bc] = wo[c] * x1;
  }
}

// ---------------- collapse conv weights ----------------
__global__ __launch_bounds__(256) void weff_kernel(const float* __restrict__ wx,
                                                   const float* __restrict__ w3,
                                                   const float* __restrict__ b3,
                                                   const float* __restrict__ bo,
                                                   float* __restrict__ weff,
                                                   float* __restrict__ beff) {
  int k = blockIdx.x;
  int b = blockIdx.y;
  int cp = threadIdx.x;
  const float* wxb = wx + b * CCH;
  if (cp < CCH) {
    float acc = 0.f;
    for (int c = 0; c < CCH; ++c)
      acc = fmaf(wxb[c], w3[((size_t)c * CCH + cp) * 9 + k], acc);
    weff[(size_t)b * (CCH * 9) + cp * 9 + k] = acc;
  }
  if (k == 0) {
    __shared__ float scratch[8];
    float p = (cp < CCH) ? wxb[cp] * b3[cp] : 0.f;
    float dummy = 0.f;
    blockReduce2(p, dummy, scratch);
    if (threadIdx.x == 0) beff[b] = p + bo[0];
  }
}

// ---------------- collapsed 3x3 conv ----------------
__global__ __launch_bounds__(256) void conv_kernel(const float* __restrict__ out,
                                                   const float* __restrict__ weff,
                                                   float* __restrict__ accum) {
  __shared__ float img[NPIX];
  int b = blockIdx.y;
  int cg = blockIdx.x;
  float racc[13];
  #pragma unroll
  for (int r = 0; r < 13; ++r) racc[r] = 0.f;
  const float* wef = weff + (size_t)b * (CCH * 9);
  for (int ci = 0; ci < 4; ++ci) {
    int cp = cg * 4 + ci;
    const float* src = out + ((size_t)b * CCH + cp) * NPIX;
    __syncthreads();
    float4* img4 = (float4*)img;
    const float4* src4 = (const float4*)src;
    for (int i = threadIdx.x; i < NPIX / 4; i += 256) img4[i] = src4[i];
    __syncthreads();
    float w[9];
    #pragma unroll
    for (int k = 0; k < 9; ++k) w[k] = wef[cp * 9 + k];
    #pragma unroll
    for (int r = 0; r < 13; ++r) {
      int i = threadIdx.x + r * 256;
      if (i < NPIX) {
        int y = i / 56, x = i - y * 56;
        float a = 0.f;
        #pragma unroll
        for (int ky = 0; ky < 3; ++ky) {
          int yy = y + ky - 1;
          if (yy < 0 || yy >= 56) continue;
          #pragma unroll
          for (int kx = 0; kx < 3; ++kx) {
            int xx = x + kx - 1;
            if (xx < 0 || xx >= 56) continue;
            a = fmaf(w[ky * 3 + kx], img[yy * 56 + xx], a);
          }
        }
        racc[r] += a;
      }
    }
  }
  #pragma unroll
  for (int r = 0; r < 13; ++r) {
    int i = threadIdx.x + r * 256;
    if (i < NPIX) atomicAdd(&accum[(size_t)b * NPIX + i], racc[r]);
  }
}

// ---------------- finalize ----------------
__global__ void fin_kernel(const float* __restrict__ accum, const float* __restrict__ beff,
                           float* __restrict__ dout) {
  int i = blockIdx.x * 256 + threadIdx.x;
  if (i < 2 * NPIX) {
    int b = i / NPIX;
    float v = accum[i] + beff[b];
    dout[i] = 1.f / (1.f + expf(-v));
  }
}

extern "C" void kernel_launch(void* const* d_in, const int* in_sizes, int n_in,
                              void* d_out, int out_size, void* d_ws, size_t ws_size,
                              hipStream_t stream) {
  (void)in_sizes; (void)n_in; (void)out_size; (void)ws_size;
  const float* D = (const float*)d_in[0];
  const float* wq = (const float*)d_in[1];
  const float* bq = (const float*)d_in[2];
  const float* wk = (const float*)d_in[3];
  const float* bk = (const float*)d_in[4];
  const float* wv = (const float*)d_in[5];
  const float* bv = (const float*)d_in[6];
  const float* gn_w = (const float*)d_in[7];
  const float* gn_b = (const float*)d_in[8];
  const float* lambda_init = (const float*)d_in[9];
  const float* lq1 = (const float*)d_in[10];
  const float* lk1 = (const float*)d_in[11];
  const float* lq2 = (const float*)d_in[12];
  const float* lk2 = (const float*)d_in[13];
  const float* w3 = (const float*)d_in[14];
  const float* b3 = (const float*)d_in[15];
  const float* wo = (const float*)d_in[16];
  const float* bo = (const float*)d_in[17];

  float* ws = (float*)d_ws;
  const size_t SZ_CHW = (size_t)2 * CCH * NPIX;
  const size_t SZ_QK = (size_t)2 * 448 * NPIX;
  float* senh = ws;
  float* Qb = senh + SZ_CHW;
  float* Kb = Qb + SZ_QK;
  float* Vb = Kb + SZ_QK;
  float* attno = Vb + SZ_CHW;
  float* wx = attno + SZ_CHW;
  float* weff = wx + 2 * CCH;
  float* beff = weff + 2 * CCH * 9;
  float* lam = beff + 2;
  float* accum = lam + 1;

  hipMemsetAsync(accum, 0, 2 * NPIX * sizeof(float), stream);
  lam_kernel<<<1, 64, 0, stream>>>(lq1, lk1, lq2, lk2, lambda_init, lam);
  prep_kernel<<<448, 256, 0, stream>>>(D, gn_w, gn_b, senh);
  gemm_kernel<<<dim3(49, 7, 2), 256, 0, stream>>>(wq, senh, bq, Qb, 448, 1, lam);
  gemm_kernel<<<dim3(49, 7, 2), 256, 0, stream>>>(wk, D, bk, Kb, 448, 0, nullptr);
  gemm_kernel<<<dim3(49, 4, 2), 256, 0, stream>>>(wv, D, bv, Vb, 224, 0, nullptr);
  attn_kernel<<<dim3(49, 7, 2), 256, 0, stream>>>(Qb, Kb, Vb, attno);
  wx_kernel<<<448, 256, 0, stream>>>(attno, wo, wx);
  weff_kernel<<<dim3(9, 2), 256, 0, stream>>>(wx, w3, b3, bo, weff, beff);
  conv_kernel<<<dim3(56, 2), 256, 0, stream>>>(attno, weff, accum);
  fin_kernel<<<25, 256, 0, stream>>>(accum, beff, (float*)d_out);
}

// Round 4
// 307.613 us; speedup vs baseline: 3.2957x; 1.1229x over previous
//
#include <hip/hip_runtime.h>
#include <math.h>

#define NPIX 3136   // 56*56
#define CCH  224
#define SCALING 0.17677669529663687f  // 32^-0.5

typedef _Float16 half8_t __attribute__((ext_vector_type(8)));
typedef _Float16 half4_t __attribute__((ext_vector_type(4)));
typedef _Float16 half2_t __attribute__((ext_vector_type(2)));
typedef float floatx4 __attribute__((ext_vector_type(4)));

// ---------------- helpers ----------------
__device__ __forceinline__ void blockReduce2(float& a, float& b, float* scratch) {
  #pragma unroll
  for (int off = 32; off > 0; off >>= 1) {
    a += __shfl_down(a, off);
    b += __shfl_down(b, off);
  }
  int wid = threadIdx.x >> 6, lane = threadIdx.x & 63;
  if (lane == 0) { scratch[wid * 2] = a; scratch[wid * 2 + 1] = b; }
  __syncthreads();
  if (threadIdx.x == 0) {
    float sa = 0.f, sb = 0.f;
    #pragma unroll
    for (int i = 0; i < 4; ++i) { sa += scratch[2 * i]; sb += scratch[2 * i + 1]; }
    scratch[0] = sa; scratch[1] = sb;
  }
  __syncthreads();
  a = scratch[0]; b = scratch[1];
}

// ---------------- lam ----------------
__global__ void lam_kernel(const float* __restrict__ lq1, const float* __restrict__ lk1,
                           const float* __restrict__ lq2, const float* __restrict__ lk2,
                           const float* __restrict__ lambda_init, float* __restrict__ lam) {
  int t = threadIdx.x;
  float p1 = (t < 32) ? lq1[t] * lk1[t] : 0.f;
  float p2 = (t < 32) ? lq2[t] * lk2[t] : 0.f;
  #pragma unroll
  for (int off = 16; off > 0; off >>= 1) {
    p1 += __shfl_down(p1, off);
    p2 += __shfl_down(p2, off);
  }
  if (t == 0) {
    float d = expf(p1) - expf(p2);
    d = fminf(fmaxf(d, 0.f), 1.f);
    lam[0] = d + lambda_init[0];
  }
}

// ---------------- prep: gating + per-channel instance norm; emits f16 senh and f16 D ----------------
__global__ __launch_bounds__(256) void prep_kernel(const float* __restrict__ D,
                                                   const float* __restrict__ gn_w,
                                                   const float* __restrict__ gn_b,
                                                   _Float16* __restrict__ senh_h,
                                                   _Float16* __restrict__ Dh) {
  __shared__ float img[NPIX];
  __shared__ float xh[56];
  __shared__ float xw[56];
  __shared__ float scratch[8];
  int bc = blockIdx.x;
  int c = bc % CCH;
  const float* src = D + (size_t)bc * NPIX;
  float4* img4 = (float4*)img;
  const float4* src4 = (const float4*)src;
  half4_t* dh4 = (half4_t*)(Dh + (size_t)bc * NPIX);
  for (int i = threadIdx.x; i < NPIX / 4; i += 256) {
    float4 v = src4[i];
    img4[i] = v;
    half4_t hv;
    hv[0] = (_Float16)v.x; hv[1] = (_Float16)v.y;
    hv[2] = (_Float16)v.z; hv[3] = (_Float16)v.w;
    dh4[i] = hv;
  }
  __syncthreads();
  if (threadIdx.x < 56) {
    int h = threadIdx.x;
    float s = 0.f;
    #pragma unroll 8
    for (int w = 0; w < 56; ++w) s += img[h * 56 + w];
    xh[h] = s * (1.f / 56.f);
  } else if (threadIdx.x >= 64 && threadIdx.x < 120) {
    int w = threadIdx.x - 64;
    float s = 0.f;
    #pragma unroll 8
    for (int h = 0; h < 56; ++h) s += img[h * 56 + w];
    xw[w] = s * (1.f / 56.f);
  }
  __syncthreads();
  float sum = 0.f, ssq = 0.f;
  for (int i = threadIdx.x; i < NPIX; i += 256) {
    int y = i / 56, x = i - y * 56;
    float d = img[i];
    float t = xh[y] + xw[x];
    float sg = 1.f / (1.f + __expf(-t));
    float g = d * sg;
    img[i] = g;
    sum += g;
    ssq += g * g;
  }
  blockReduce2(sum, ssq, scratch);
  float mu = sum * (1.f / (float)NPIX);
  float var = ssq * (1.f / (float)NPIX) - mu * mu;
  float rstd = rsqrtf(var + 1e-5f);
  float a = gn_w[c] * rstd;
  float bb = gn_b[c] - mu * a;
  _Float16* dst = senh_h + (size_t)bc * NPIX;
  for (int i = threadIdx.x; i < NPIX; i += 256) dst[i] = (_Float16)fmaf(img[i], a, bb);
}

// ---------------- f16 MFMA GEMM for the 1x1 convs ----------------
// W fp32 [M][224], Xh f16 [224][NPIX] per batch.
// mode 0: Y = Vt f16 [b][M][NPIX] channel-major
// mode 1: Y = Qt f16 [b][7][NPIX][64], bias then scale (s / -lam*s)
// mode 2: Y = Kt f16 [b][7][NPIX][64], bias only
__global__ __launch_bounds__(256) void gemm_f16_kernel(const float* __restrict__ W,
                                                       const _Float16* __restrict__ Xh,
                                                       const float* __restrict__ bias,
                                                       _Float16* __restrict__ Y, int M, int mode,
                                                       const float* __restrict__ lamp) {
  __shared__ _Float16 Ws[64][232];   // pad 232: b128 reads spread evenly
  __shared__ _Float16 Xs[64][40];    // n-major, pad 40: rows 80B (16B-aligned)
  int b = blockIdx.z;
  int r0 = blockIdx.y * 64, n0 = blockIdx.x * 64;
  const _Float16* Xb = Xh + (size_t)b * CCH * NPIX;
  int tid = threadIdx.x;
  int w = tid >> 6, lane = tid & 63, q = lane & 15, g = lane >> 4;

  // stage W tile (fp32 -> f16), zero-padded past M
  for (int i = tid; i < 64 * 224; i += 256) {
    int r = i / 224, cc = i - r * 224;
    float wv = (r0 + r < M) ? W[(size_t)(r0 + r) * CCH + cc] : 0.f;
    Ws[r][cc] = (_Float16)wv;
  }

  floatx4 acc[4];
  #pragma unroll
  for (int t = 0; t < 4; ++t)
    #pragma unroll
    for (int r = 0; r < 4; ++r) acc[t][r] = 0.f;

  int cp = tid & 15, ng = tid >> 4;   // staging: 2 channels x 4 pixels each
  #pragma unroll
  for (int kc = 0; kc < 7; ++kc) {
    const _Float16* x0 = Xb + (size_t)(kc * 32 + 2 * cp) * NPIX + n0 + ng * 4;
    half4_t xa = *(const half4_t*)x0;
    half4_t xb = *(const half4_t*)(x0 + NPIX);
    __syncthreads();   // previous iteration's reads complete
    #pragma unroll
    for (int j = 0; j < 4; ++j) {
      half2_t hw; hw[0] = xa[j]; hw[1] = xb[j];
      *(half2_t*)&Xs[ng * 4 + j][2 * cp] = hw;
    }
    __syncthreads();   // Xs (and first-iter Ws) visible
    half8_t ka = *(const half8_t*)&Ws[w * 16 + q][kc * 32 + g * 8];
    #pragma unroll
    for (int t = 0; t < 4; ++t) {
      half8_t xfrag = *(const half8_t*)&Xs[16 * t + q][g * 8];
      acc[t] = __builtin_amdgcn_mfma_f32_16x16x32_f16(ka, xfrag, acc[t], 0, 0, 0);
    }
  }
  __syncthreads();   // Ws reads done; reuse as C tile

  float lamv = (mode == 1) ? lamp[0] : 0.f;
  _Float16* Cs = &Ws[0][0];   // [64][72] f16 view
  #pragma unroll
  for (int t = 0; t < 4; ++t) {
    #pragma unroll
    for (int r = 0; r < 4; ++r) {
      int m = w * 16 + 4 * g + r;
      int n = 16 * t + q;
      int gm = r0 + m;
      float v = 0.f;
      if (gm < M) {
        v = acc[t][r] + bias[gm];
        if (mode == 1) v *= (gm < CCH) ? SCALING : (-lamv * SCALING);
      }
      Cs[m * 72 + n] = (_Float16)v;
    }
  }
  __syncthreads();

  if (mode == 0) {
    int row = tid >> 2, oct = tid & 3;
    if (r0 + row < M) {
      half8_t u0 = *(half8_t*)&Cs[row * 72 + oct * 16];
      half8_t u1 = *(half8_t*)&Cs[row * 72 + oct * 16 + 8];
      _Float16* dst = Y + ((size_t)b * M + r0 + row) * NPIX + n0 + oct * 16;
      *(half8_t*)dst = u0;
      *(half8_t*)(dst + 8) = u1;
    }
  } else {
    int n = tid & 63, quarter = tid >> 6;
    int vbase = r0 + quarter * 16;
    int chunk = vbase >= CCH;
    int ch_in = vbase - chunk * CCH;
    int hh = ch_in >> 5;
    int dstart = chunk * 32 + (ch_in & 31);
    _Float16 tmp[16];
    #pragma unroll
    for (int i = 0; i < 16; ++i) tmp[i] = Cs[(quarter * 16 + i) * 72 + n];
    _Float16* dst = Y + (((size_t)b * 7 + hh) * NPIX + (n0 + n)) * 64 + dstart;
    *(half8_t*)dst = *(half8_t*)&tmp[0];
    *(half8_t*)(dst + 8) = *(half8_t*)&tmp[8];
  }
}

// ---------------- MFMA flash attention, pipelined + double-buffered ----------------
// Qt/Kt: [b][7][n][64] f16 (Q pre-scaled), Vt: [b][224][n] f16.
__global__ __launch_bounds__(256) void attn_kernel(const _Float16* __restrict__ Qt,
                                                   const _Float16* __restrict__ Kt,
                                                   const _Float16* __restrict__ Vt,
                                                   float* __restrict__ out) {
  __shared__ _Float16 K_lds[2][64][72];
  __shared__ _Float16 V_lds[2][32][72];
  __shared__ _Float16 P_lds[64][72];

  // bijective XCD swizzle (686 = 8*85 + 6): each XCD gets ~86 consecutive ids
  int orig = blockIdx.x;
  int xcd = orig & 7, off = orig >> 3;
  int wg = (xcd < 6) ? xcd * 86 + off : 6 * 86 + (xcd - 6) * 85 + off;
  int qt = wg % 49;
  int hb = wg / 49;
  int h = hb % 7, b = hb / 7;

  int tid = threadIdx.x;
  int w = tid >> 6, lane = tid & 63;
  int q = lane & 15, g = lane >> 4;
  int nq = qt * 64 + w * 16 + q;

  const _Float16* Qb = Qt + ((size_t)(b * 7 + h) * NPIX + nq) * 64;
  const _Float16* Kb = Kt + (size_t)(b * 7 + h) * NPIX * 64;
  const _Float16* Vb = Vt + ((size_t)b * CCH + h * 32) * NPIX;

  half8_t qv[2];
  qv[0] = *(const half8_t*)(Qb + g * 8);
  qv[1] = *(const half8_t*)(Qb + 32 + g * 8);

  floatx4 oacc[2];
  #pragma unroll
  for (int dt = 0; dt < 2; ++dt)
    #pragma unroll
    for (int r = 0; r < 4; ++r) oacc[dt][r] = 0.f;
  float mrun = -INFINITY, lrun = 0.f;

  // staging assignment (straight copies)
  int kkey = tid >> 2, koct = (tid & 3) * 16;               // K: 64 keys x 32B
  const _Float16* ksrc = Kb + (size_t)kkey * 64 + koct;     // + m0*64
  int vd = tid >> 3, voff = (tid & 7) * 8;                  // V: 32 dims x 16B
  const _Float16* vsrc = Vb + (size_t)vd * NPIX + voff;     // + m0

  half8_t kr0, kr1, vr;
  // prologue: tile 0
  {
    kr0 = *(const half8_t*)(ksrc);
    kr1 = *(const half8_t*)(ksrc + 8);
    vr = *(const half8_t*)(vsrc);
    *(half8_t*)&K_lds[0][kkey][koct] = kr0;
    *(half8_t*)&K_lds[0][kkey][koct + 8] = kr1;
    *(half8_t*)&V_lds[0][vd][voff] = vr;
  }
  __syncthreads();

  for (int kc = 0; kc < 49; ++kc) {
    int cur = kc & 1;
    if (kc < 48) {   // prefetch next tile into regs (latency spans compute)
      size_t m0 = (size_t)(kc + 1) * 64;
      kr0 = *(const half8_t*)(ksrc + m0 * 64);
      kr1 = *(const half8_t*)(ksrc + m0 * 64 + 8);
      vr = *(const half8_t*)(vsrc + m0);
    }

    // ---- QK^T: S^T[key][q] ----
    floatx4 sacc[4];
    #pragma unroll
    for (int t = 0; t < 4; ++t)
      #pragma unroll
      for (int r = 0; r < 4; ++r) sacc[t][r] = 0.f;
    #pragma unroll
    for (int t = 0; t < 4; ++t) {
      #pragma unroll
      for (int c = 0; c < 2; ++c) {
        half8_t ka = *(const half8_t*)&K_lds[cur][t * 16 + q][c * 32 + g * 8];
        sacc[t] = __builtin_amdgcn_mfma_f32_16x16x32_f16(ka, qv[c], sacc[t], 0, 0, 0);
      }
    }

    // ---- online softmax (per q = lane&15; key split across g + tiles) ----
    float tmax = sacc[0][0];
    #pragma unroll
    for (int t = 0; t < 4; ++t)
      #pragma unroll
      for (int r = 0; r < 4; ++r) tmax = fmaxf(tmax, sacc[t][r]);
    tmax = fmaxf(tmax, __shfl_xor(tmax, 16));
    tmax = fmaxf(tmax, __shfl_xor(tmax, 32));
    float mnew = fmaxf(mrun, tmax);
    float corr = __expf(mrun - mnew);
    float lsum = 0.f;
    #pragma unroll
    for (int t = 0; t < 4; ++t)
      #pragma unroll
      for (int r = 0; r < 4; ++r) {
        float p = __expf(sacc[t][r] - mnew);
        sacc[t][r] = p;
        lsum += p;
      }
    lsum += __shfl_xor(lsum, 16);
    lsum += __shfl_xor(lsum, 32);
    lrun = lrun * corr + lsum;
    #pragma unroll
    for (int dt = 0; dt < 2; ++dt)
      #pragma unroll
      for (int r = 0; r < 4; ++r) oacc[dt][r] *= corr;
    mrun = mnew;

    // ---- P -> f16 -> per-wave LDS rows ----
    #pragma unroll
    for (int t = 0; t < 4; ++t) {
      half4_t ph;
      ph[0] = (_Float16)sacc[t][0];
      ph[1] = (_Float16)sacc[t][1];
      ph[2] = (_Float16)sacc[t][2];
      ph[3] = (_Float16)sacc[t][3];
      *(half4_t*)&P_lds[w * 16 + q][t * 16 + g * 4] = ph;
    }

    // ---- PV: O^T[d][q] += V[d][m] * P[m][q] ----
    #pragma unroll
    for (int dt = 0; dt < 2; ++dt) {
      #pragma unroll
      for (int c = 0; c < 2; ++c) {
        half8_t va = *(const half8_t*)&V_lds[cur][dt * 16 + q][c * 32 + g * 8];
        half8_t pb = *(const half8_t*)&P_lds[w * 16 + q][c * 32 + g * 8];
        oacc[dt] = __builtin_amdgcn_mfma_f32_16x16x32_f16(va, pb, oacc[dt], 0, 0, 0);
      }
    }

    if (kc < 48) {   // write prefetched tile into the other buffer
      *(half8_t*)&K_lds[cur ^ 1][kkey][koct] = kr0;
      *(half8_t*)&K_lds[cur ^ 1][kkey][koct + 8] = kr1;
      *(half8_t*)&V_lds[cur ^ 1][vd][voff] = vr;
    }
    __syncthreads();
  }

  // ---- finalize: normalize, LDS transpose, coalesced fp32 write ----
  float* out_lds = (float*)&K_lds[0][0][0];   // 32*68*4 = 8704B
  float inv = 1.f / lrun;
  #pragma unroll
  for (int dt = 0; dt < 2; ++dt)
    #pragma unroll
    for (int r = 0; r < 4; ++r) {
      int d = dt * 16 + g * 4 + r;
      out_lds[d * 68 + w * 16 + q] = oacc[dt][r] * inv;
    }
  __syncthreads();
  {
    int d = tid >> 3;
    int i8 = (tid & 7) << 3;
    float4 u0 = *(float4*)&out_lds[d * 68 + i8];
    float4 u1 = *(float4*)&out_lds[d * 68 + i8 + 4];
    float* dst = out + ((size_t)b * CCH + h * 32 + d) * NPIX + qt * 64 + i8;
    *(float4*)dst = u0;
    *(float4*)(dst + 4) = u1;
  }
}

// ---------------- channel means -> wx = wo*sigmoid(mean); beff += wx*b3 ----------------
__global__ __launch_bounds__(256) void wx_kernel(const float* __restrict__ out,
                                                 const float* __restrict__ wo,
                                                 const float* __restrict__ b3,
                                                 float* __restrict__ wx,
                                                 float* __restrict__ beff) {
  __shared__ float scratch[8];
  int bc = blockIdx.x;
  int c = bc % CCH;
  int b = bc / CCH;
  const float* src = out + (size_t)bc * NPIX;
  float s = 0.f, dummy = 0.f;
  for (int i = threadIdx.x; i < NPIX; i += 256) s += src[i];
  blockReduce2(s, dummy, scratch);
  if (threadIdx.x == 0) {
    float mean = s * (1.f / (float)NPIX);
    float x1 = 1.f / (1.f + expf(-mean));
    float v = wo[c] * x1;
    wx[bc] = v;
    atomicAdd(&beff[b], v * b3[c]);
  }
}

// ---------------- weff[b][cp*9+k] = sum_c wx[b][c]*w3[c][cp*9+k] (coalesced GEMV) ----------------
__global__ void weff_kernel(const float* __restrict__ wx, const float* __restrict__ w3,
                            float* __restrict__ weff) {
  int t = blockIdx.x * 256 + threadIdx.x;
  if (t < 2 * 2016) {
    int b = t / 2016, rem = t - b * 2016;
    const float* wxb = wx + b * CCH;
    float acc = 0.f;
    #pragma unroll 4
    for (int c = 0; c < CCH; ++c) acc = fmaf(wxb[c], w3[(size_t)c * 2016 + rem], acc);
    weff[t] = acc;
  }
}

// ---------------- per-channel 3x3 conv with collapsed weights ----------------
__global__ __launch_bounds__(256) void conv1_kernel(const float* __restrict__ attno,
                                                    const float* __restrict__ weff,
                                                    float* __restrict__ convout) {
  __shared__ float img[NPIX];
  int bc = blockIdx.x;
  int b = bc / CCH, cp = bc % CCH;
  const float* src = attno + (size_t)bc * NPIX;
  float4* img4 = (float4*)img;
  const float4* src4 = (const float4*)src;
  for (int i = threadIdx.x; i < NPIX / 4; i += 256) img4[i] = src4[i];
  __syncthreads();
  float w[9];
  #pragma unroll
  for (int k = 0; k < 9; ++k) w[k] = weff[b * 2016 + cp * 9 + k];
  float* dst = convout + (size_t)bc * NPIX;
  #pragma unroll
  for (int r = 0; r < 13; ++r) {
    int i = threadIdx.x + r * 256;
    if (i < NPIX) {
      int y = i / 56, x = i - y * 56;
      float a = 0.f;
      #pragma unroll
      for (int ky = 0; ky < 3; ++ky) {
        int yy = y + ky - 1;
        if (yy < 0 || yy >= 56) continue;
        #pragma unroll
        for (int kx = 0; kx < 3; ++kx) {
          int xx = x + kx - 1;
          if (xx < 0 || xx >= 56) continue;
          a = fmaf(w[ky * 3 + kx], img[yy * 56 + xx], a);
        }
      }
      dst[i] = a;
    }
  }
}

// ---------------- channel-sum + bias + sigmoid -> final output ----------------
__global__ void conv2_kernel(const float* __restrict__ convout, const float* __restrict__ beff,
                             const float* __restrict__ bo, float* __restrict__ dout) {
  int px = blockIdx.x * 256 + threadIdx.x;
  int b = blockIdx.y;
  if (px < NPIX) {
    const float* src = convout + (size_t)b * CCH * NPIX + px;
    float s = 0.f;
    #pragma unroll 8
    for (int c = 0; c < CCH; ++c) s += src[(size_t)c * NPIX];
    float v = s + beff[b] + bo[0];
    dout[b * NPIX + px] = 1.f / (1.f + expf(-v));
  }
}

extern "C" void kernel_launch(void* const* d_in, const int* in_sizes, int n_in,
                              void* d_out, int out_size, void* d_ws, size_t ws_size,
                              hipStream_t stream) {
  (void)in_sizes; (void)n_in; (void)out_size; (void)ws_size;
  const float* D = (const float*)d_in[0];
  const float* wq = (const float*)d_in[1];
  const float* bq = (const float*)d_in[2];
  const float* wk = (const float*)d_in[3];
  const float* bk = (const float*)d_in[4];
  const float* wv = (const float*)d_in[5];
  const float* bv = (const float*)d_in[6];
  const float* gn_w = (const float*)d_in[7];
  const float* gn_b = (const float*)d_in[8];
  const float* lambda_init = (const float*)d_in[9];
  const float* lq1 = (const float*)d_in[10];
  const float* lk1 = (const float*)d_in[11];
  const float* lq2 = (const float*)d_in[12];
  const float* lk2 = (const float*)d_in[13];
  const float* w3 = (const float*)d_in[14];
  const float* b3 = (const float*)d_in[15];
  const float* wo = (const float*)d_in[16];
  const float* bo = (const float*)d_in[17];

  const size_t SZ_CHW = (size_t)2 * CCH * NPIX;   // 1,404,928
  const size_t SZ_QK = (size_t)2 * 7 * NPIX * 64; // 2,809,856
  _Float16* Dh = (_Float16*)d_ws;
  _Float16* senh_h = Dh + SZ_CHW;
  _Float16* Qt = senh_h + SZ_CHW;
  _Float16* Kt = Qt + SZ_QK;
  _Float16* Vt = Kt + SZ_QK;
  float* attno = (float*)(Vt + SZ_CHW);
  float* convout = attno + SZ_CHW;
  float* wx = convout + SZ_CHW;
  float* weff = wx + 2 * CCH;
  float* beff = weff + 2 * CCH * 9;
  float* lam = beff + 2;

  hipMemsetAsync(beff, 0, 2 * sizeof(float), stream);
  lam_kernel<<<1, 64, 0, stream>>>(lq1, lk1, lq2, lk2, lambda_init, lam);
  prep_kernel<<<448, 256, 0, stream>>>(D, gn_w, gn_b, senh_h, Dh);
  gemm_f16_kernel<<<dim3(49, 7, 2), 256, 0, stream>>>(wq, senh_h, bq, Qt, 448, 1, lam);
  gemm_f16_kernel<<<dim3(49, 7, 2), 256, 0, stream>>>(wk, Dh, bk, Kt, 448, 2, nullptr);
  gemm_f16_kernel<<<dim3(49, 4, 2), 256, 0, stream>>>(wv, Dh, bv, Vt, 224, 0, nullptr);
  attn_kernel<<<686, 256, 0, stream>>>(Qt, Kt, Vt, attno);
  wx_kernel<<<448, 256, 0, stream>>>(attno, wo, b3, wx, beff);
  weff_kernel<<<16, 256, 0, stream>>>(wx, w3, weff);
  conv1_kernel<<<448, 256, 0, stream>>>(attno, weff, convout);
  conv2_kernel<<<dim3(13, 2), 256, 0, stream>>>(convout, beff, bo, (float*)d_out);
}

// Round 5
// 238.679 us; speedup vs baseline: 4.2476x; 1.2888x over previous
//
#include <hip/hip_runtime.h>
#include <math.h>

#define NPIX 3136   // 56*56
#define CCH  224
#define SCALING 0.17677669529663687f   // 32^-0.5
#define LOG2E 1.4426950408889634f
#define SCL2 (SCALING * LOG2E)         // folded into Q: logits in log2 domain

typedef _Float16 half8_t __attribute__((ext_vector_type(8)));
typedef _Float16 half4_t __attribute__((ext_vector_type(4)));
typedef _Float16 half2_t __attribute__((ext_vector_type(2)));
typedef float floatx4 __attribute__((ext_vector_type(4)));

__device__ __forceinline__ float exp2fast(float x) { return __builtin_amdgcn_exp2f(x); }

// ---------------- helpers ----------------
__device__ __forceinline__ void blockReduce2(float& a, float& b, float* scratch) {
  #pragma unroll
  for (int off = 32; off > 0; off >>= 1) {
    a += __shfl_down(a, off);
    b += __shfl_down(b, off);
  }
  int wid = threadIdx.x >> 6, lane = threadIdx.x & 63;
  if (lane == 0) { scratch[wid * 2] = a; scratch[wid * 2 + 1] = b; }
  __syncthreads();
  if (threadIdx.x == 0) {
    float sa = 0.f, sb = 0.f;
    #pragma unroll
    for (int i = 0; i < 4; ++i) { sa += scratch[2 * i]; sb += scratch[2 * i + 1]; }
    scratch[0] = sa; scratch[1] = sb;
  }
  __syncthreads();
  a = scratch[0]; b = scratch[1];
}

// ---------------- lam ----------------
__global__ void lam_kernel(const float* __restrict__ lq1, const float* __restrict__ lk1,
                           const float* __restrict__ lq2, const float* __restrict__ lk2,
                           const float* __restrict__ lambda_init, float* __restrict__ lam) {
  int t = threadIdx.x;
  float p1 = (t < 32) ? lq1[t] * lk1[t] : 0.f;
  float p2 = (t < 32) ? lq2[t] * lk2[t] : 0.f;
  #pragma unroll
  for (int off = 16; off > 0; off >>= 1) {
    p1 += __shfl_down(p1, off);
    p2 += __shfl_down(p2, off);
  }
  if (t == 0) {
    float d = expf(p1) - expf(p2);
    d = fminf(fmaxf(d, 0.f), 1.f);
    lam[0] = d + lambda_init[0];
  }
}

// ---------------- prep: gating + per-channel instance norm; emits f16 senh and f16 D ----------------
__global__ __launch_bounds__(256) void prep_kernel(const float* __restrict__ D,
                                                   const float* __restrict__ gn_w,
                                                   const float* __restrict__ gn_b,
                                                   _Float16* __restrict__ senh_h,
                                                   _Float16* __restrict__ Dh) {
  __shared__ float img[NPIX];
  __shared__ float xh[56];
  __shared__ float xw[56];
  __shared__ float scratch[8];
  int bc = blockIdx.x;
  int c = bc % CCH;
  const float* src = D + (size_t)bc * NPIX;
  float4* img4 = (float4*)img;
  const float4* src4 = (const float4*)src;
  half4_t* dh4 = (half4_t*)(Dh + (size_t)bc * NPIX);
  for (int i = threadIdx.x; i < NPIX / 4; i += 256) {
    float4 v = src4[i];
    img4[i] = v;
    half4_t hv;
    hv[0] = (_Float16)v.x; hv[1] = (_Float16)v.y;
    hv[2] = (_Float16)v.z; hv[3] = (_Float16)v.w;
    dh4[i] = hv;
  }
  __syncthreads();
  if (threadIdx.x < 56) {
    int h = threadIdx.x;
    float s = 0.f;
    #pragma unroll 8
    for (int w = 0; w < 56; ++w) s += img[h * 56 + w];
    xh[h] = s * (1.f / 56.f);
  } else if (threadIdx.x >= 64 && threadIdx.x < 120) {
    int w = threadIdx.x - 64;
    float s = 0.f;
    #pragma unroll 8
    for (int h = 0; h < 56; ++h) s += img[h * 56 + w];
    xw[w] = s * (1.f / 56.f);
  }
  __syncthreads();
  float sum = 0.f, ssq = 0.f;
  for (int i = threadIdx.x; i < NPIX; i += 256) {
    int y = i / 56, x = i - y * 56;
    float d = img[i];
    float t = xh[y] + xw[x];
    float sg = 1.f / (1.f + __expf(-t));
    float g = d * sg;
    img[i] = g;
    sum += g;
    ssq += g * g;
  }
  blockReduce2(sum, ssq, scratch);
  float mu = sum * (1.f / (float)NPIX);
  float var = ssq * (1.f / (float)NPIX) - mu * mu;
  float rstd = rsqrtf(var + 1e-5f);
  float a = gn_w[c] * rstd;
  float bb = gn_b[c] - mu * a;
  _Float16* dst = senh_h + (size_t)bc * NPIX;
  for (int i = threadIdx.x; i < NPIX; i += 256) dst[i] = (_Float16)fmaf(img[i], a, bb);
}

// ---------------- convert conv weights to f16 once ----------------
__global__ void wcvt_kernel(const float* __restrict__ wq, const float* __restrict__ wk,
                            const float* __restrict__ wv,
                            _Float16* __restrict__ whq, _Float16* __restrict__ whk,
                            _Float16* __restrict__ whv) {
  int i = blockIdx.x * 256 + threadIdx.x;   // float4 index
  const int NQ = 448 * 224 / 4;             // 25088
  const int NV = 224 * 224 / 4;             // 12544
  const float* src; _Float16* dst; int off;
  if (i < NQ) { src = wq; dst = whq; off = i; }
  else if (i < 2 * NQ) { src = wk; dst = whk; off = i - NQ; }
  else if (i < 2 * NQ + NV) { src = wv; dst = whv; off = i - 2 * NQ; }
  else return;
  float4 v = ((const float4*)src)[off];
  half4_t h;
  h[0] = (_Float16)v.x; h[1] = (_Float16)v.y;
  h[2] = (_Float16)v.z; h[3] = (_Float16)v.w;
  ((half4_t*)dst)[off] = h;
}

// ---------------- f16 MFMA GEMM for the 1x1 convs (W fragments in registers) ----------------
// Wh f16 [M][224], Xh f16 [224][NPIX] per batch.
// mode 0: Y = Vt f16 [b][M][NPIX] channel-major
// mode 1: Y = Qt f16 [b][7][NPIX][64], bias then scale (s*log2e / -lam*s*log2e)
// mode 2: Y = Kt f16 [b][7][NPIX][64], bias only
__global__ __launch_bounds__(256) void gemm_f16_kernel(const _Float16* __restrict__ Wh,
                                                       const _Float16* __restrict__ Xh,
                                                       const float* __restrict__ bias,
                                                       _Float16* __restrict__ Y, int M, int mode,
                                                       const float* __restrict__ lamp) {
  __shared__ _Float16 Xs[64][40];    // n-major, pad 40 (rows 80B)
  __shared__ _Float16 Cs[64][72];
  int b = blockIdx.z;
  int r0 = blockIdx.y * 64, n0 = blockIdx.x * 64;
  const _Float16* Xb = Xh + (size_t)b * CCH * NPIX;
  int tid = threadIdx.x;
  int w = tid >> 6, lane = tid & 63, q = lane & 15, g = lane >> 4;

  int wrow = r0 + w * 16 + q;
  if (wrow >= M) wrow = M - 1;               // guarded at epilogue
  half8_t wfrag[7];
  #pragma unroll
  for (int kc = 0; kc < 7; ++kc)
    wfrag[kc] = *(const half8_t*)&Wh[(size_t)wrow * 224 + kc * 32 + g * 8];

  floatx4 acc[4];
  #pragma unroll
  for (int t = 0; t < 4; ++t)
    #pragma unroll
    for (int r = 0; r < 4; ++r) acc[t][r] = 0.f;

  int cp = tid & 15, ng = tid >> 4;   // staging: 2 channels x 4 pixels
  #pragma unroll
  for (int kc = 0; kc < 7; ++kc) {
    const _Float16* x0 = Xb + (size_t)(kc * 32 + 2 * cp) * NPIX + n0 + ng * 4;
    half4_t xa = *(const half4_t*)x0;
    half4_t xb = *(const half4_t*)(x0 + NPIX);
    if (kc) __syncthreads();   // previous iteration's Xs reads complete
    #pragma unroll
    for (int j = 0; j < 4; ++j) {
      half2_t hw; hw[0] = xa[j]; hw[1] = xb[j];
      *(half2_t*)&Xs[ng * 4 + j][2 * cp] = hw;
    }
    __syncthreads();
    #pragma unroll
    for (int t = 0; t < 4; ++t) {
      half8_t xfrag = *(const half8_t*)&Xs[16 * t + q][g * 8];
      acc[t] = __builtin_amdgcn_mfma_f32_16x16x32_f16(wfrag[kc], xfrag, acc[t], 0, 0, 0);
    }
  }

  float lamv = (mode == 1) ? lamp[0] : 0.f;
  #pragma unroll
  for (int t = 0; t < 4; ++t) {
    #pragma unroll
    for (int r = 0; r < 4; ++r) {
      int m = w * 16 + 4 * g + r;
      int n = 16 * t + q;
      int gm = r0 + m;
      float v = 0.f;
      if (gm < M) {
        v = acc[t][r] + bias[gm];
        if (mode == 1) v *= (gm < CCH) ? SCL2 : (-lamv * SCL2);
      }
      Cs[m][n] = (_Float16)v;
    }
  }
  __syncthreads();

  if (mode == 0) {
    int row = tid >> 2, oct = tid & 3;
    if (r0 + row < M) {
      half8_t u0 = *(half8_t*)&Cs[row][oct * 16];
      half8_t u1 = *(half8_t*)&Cs[row][oct * 16 + 8];
      _Float16* dst = Y + ((size_t)b * M + r0 + row) * NPIX + n0 + oct * 16;
      *(half8_t*)dst = u0;
      *(half8_t*)(dst + 8) = u1;
    }
  } else {
    int n = tid & 63, quarter = tid >> 6;
    int vbase = r0 + quarter * 16;
    int chunk = vbase >= CCH;
    int ch_in = vbase - chunk * CCH;
    int hh = ch_in >> 5;
    int dstart = chunk * 32 + (ch_in & 31);
    _Float16 tmp[16];
    #pragma unroll
    for (int i = 0; i < 16; ++i) tmp[i] = Cs[quarter * 16 + i][n];
    _Float16* dst = Y + (((size_t)b * 7 + hh) * NPIX + (n0 + n)) * 64 + dstart;
    *(half8_t*)dst = *(half8_t*)&tmp[0];
    *(half8_t*)(dst + 8) = *(half8_t*)&tmp[8];
  }
}

// ---------------- MFMA flash attention, split-K x2 + exp2 + defer-max ----------------
// Qt/Kt: [b][7][n][64] f16 (Q pre-scaled by s*log2e), Vt: [b][224][n] f16.
// grid 1372 = 14 bh * 2 seg * 49 qt. Partial outputs (un-normalized) + (m,l).
__global__ __launch_bounds__(256) void attn_part_kernel(const _Float16* __restrict__ Qt,
                                                        const _Float16* __restrict__ Kt,
                                                        const _Float16* __restrict__ Vt,
                                                        float* __restrict__ Opart,
                                                        float2* __restrict__ ml2) {
  __shared__ _Float16 K_lds[2][64][72];
  __shared__ _Float16 V_lds[2][32][72];
  __shared__ _Float16 P_lds[64][72];

  // bijective XCD swizzle over 1372 = 8*171 + 4
  int orig = blockIdx.x;
  int xcd = orig & 7, off = orig >> 3;
  int wg = (xcd < 4) ? xcd * 172 + off : 4 * 172 + (xcd - 4) * 171 + off;
  int qt = wg % 49;
  int rest = wg / 49;
  int seg = rest & 1, bh = rest >> 1;
  int h = bh % 7, b = bh / 7;
  int t0 = seg ? 25 : 0;
  int nt = seg ? 24 : 25;

  int tid = threadIdx.x;
  int w = tid >> 6, lane = tid & 63;
  int q = lane & 15, g = lane >> 4;
  int nq = qt * 64 + w * 16 + q;

  const _Float16* Qb = Qt + ((size_t)(b * 7 + h) * NPIX + nq) * 64;
  const _Float16* Kb = Kt + (size_t)(b * 7 + h) * NPIX * 64;
  const _Float16* Vb = Vt + ((size_t)b * CCH + h * 32) * NPIX;

  half8_t qv[2];
  qv[0] = *(const half8_t*)(Qb + g * 8);
  qv[1] = *(const half8_t*)(Qb + 32 + g * 8);

  floatx4 oacc[2];
  #pragma unroll
  for (int dt = 0; dt < 2; ++dt)
    #pragma unroll
    for (int r = 0; r < 4; ++r) oacc[dt][r] = 0.f;
  float mrun = -INFINITY, lrun = 0.f;

  int kkey = tid >> 2, koct = (tid & 3) * 16;
  const _Float16* ksrc = Kb + ((size_t)t0 * 64 + kkey) * 64 + koct;
  int vd = tid >> 3, voff = (tid & 7) * 8;
  const _Float16* vsrc = Vb + (size_t)vd * NPIX + t0 * 64 + voff;

  half8_t kr0, kr1, vr;
  kr0 = *(const half8_t*)(ksrc);
  kr1 = *(const half8_t*)(ksrc + 8);
  vr = *(const half8_t*)(vsrc);
  *(half8_t*)&K_lds[0][kkey][koct] = kr0;
  *(half8_t*)&K_lds[0][kkey][koct + 8] = kr1;
  *(half8_t*)&V_lds[0][vd][voff] = vr;
  __syncthreads();

  for (int kc = 0; kc < nt; ++kc) {
    int cur = kc & 1;
    if (kc < nt - 1) {
      size_t m0 = (size_t)(kc + 1) * 64;
      kr0 = *(const half8_t*)(ksrc + m0 * 64);
      kr1 = *(const half8_t*)(ksrc + m0 * 64 + 8);
      vr = *(const half8_t*)(vsrc + m0);
    }

    // ---- QK^T (log2-domain logits) ----
    floatx4 sacc[4];
    #pragma unroll
    for (int t = 0; t < 4; ++t)
      #pragma unroll
      for (int r = 0; r < 4; ++r) sacc[t][r] = 0.f;
    #pragma unroll
    for (int t = 0; t < 4; ++t) {
      #pragma unroll
      for (int c = 0; c < 2; ++c) {
        half8_t ka = *(const half8_t*)&K_lds[cur][t * 16 + q][c * 32 + g * 8];
        sacc[t] = __builtin_amdgcn_mfma_f32_16x16x32_f16(ka, qv[c], sacc[t], 0, 0, 0);
      }
    }

    // ---- online softmax, defer-max (THR=8 in log2 units -> P <= 256) ----
    float tmax = fmaxf(fmaxf(sacc[0][0], sacc[0][1]), fmaxf(sacc[0][2], sacc[0][3]));
    #pragma unroll
    for (int t = 1; t < 4; ++t)
      tmax = fmaxf(tmax, fmaxf(fmaxf(sacc[t][0], sacc[t][1]), fmaxf(sacc[t][2], sacc[t][3])));
    tmax = fmaxf(tmax, __shfl_xor(tmax, 16));
    tmax = fmaxf(tmax, __shfl_xor(tmax, 32));
    if (__any(tmax > mrun + 8.f)) {
      float mnew = fmaxf(mrun, tmax);
      float corr = exp2fast(mrun - mnew);
      lrun *= corr;
      #pragma unroll
      for (int dt = 0; dt < 2; ++dt)
        #pragma unroll
        for (int r = 0; r < 4; ++r) oacc[dt][r] *= corr;
      mrun = mnew;
    }
    float lsum = 0.f;
    #pragma unroll
    for (int t = 0; t < 4; ++t)
      #pragma unroll
      for (int r = 0; r < 4; ++r) {
        float p = exp2fast(sacc[t][r] - mrun);
        sacc[t][r] = p;
        lsum += p;
      }
    lsum += __shfl_xor(lsum, 16);
    lsum += __shfl_xor(lsum, 32);
    lrun += lsum;

    // ---- P -> f16 -> per-wave LDS rows ----
    #pragma unroll
    for (int t = 0; t < 4; ++t) {
      half4_t ph;
      ph[0] = (_Float16)sacc[t][0];
      ph[1] = (_Float16)sacc[t][1];
      ph[2] = (_Float16)sacc[t][2];
      ph[3] = (_Float16)sacc[t][3];
      *(half4_t*)&P_lds[w * 16 + q][t * 16 + g * 4] = ph;
    }

    // ---- PV ----
    #pragma unroll
    for (int dt = 0; dt < 2; ++dt) {
      #pragma unroll
      for (int c = 0; c < 2; ++c) {
        half8_t va = *(const half8_t*)&V_lds[cur][dt * 16 + q][c * 32 + g * 8];
        half8_t pb = *(const half8_t*)&P_lds[w * 16 + q][c * 32 + g * 8];
        oacc[dt] = __builtin_amdgcn_mfma_f32_16x16x32_f16(va, pb, oacc[dt], 0, 0, 0);
      }
    }

    if (kc < nt - 1) {
      *(half8_t*)&K_lds[cur ^ 1][kkey][koct] = kr0;
      *(half8_t*)&K_lds[cur ^ 1][kkey][koct + 8] = kr1;
      *(half8_t*)&V_lds[cur ^ 1][vd][voff] = vr;
    }
    __syncthreads();
  }

  // ---- write partials: transpose via LDS, coalesced ----
  size_t pbase = (((size_t)bh * 2 + seg) * 49 + qt);
  float* out_lds = (float*)&K_lds[0][0][0];   // 32*68*4 = 8704B
  #pragma unroll
  for (int dt = 0; dt < 2; ++dt)
    #pragma unroll
    for (int r = 0; r < 4; ++r) {
      int d = dt * 16 + g * 4 + r;
      out_lds[d * 68 + w * 16 + q] = oacc[dt][r];
    }
  if (lane < 16) ml2[pbase * 64 + w * 16 + lane] = make_float2(mrun, lrun);
  __syncthreads();
  {
    int d = tid >> 3;
    int i8 = (tid & 7) << 3;
    float4 u0 = *(float4*)&out_lds[d * 68 + i8];
    float4 u1 = *(float4*)&out_lds[d * 68 + i8 + 4];
    float* dst = Opart + pbase * 2048 + d * 64 + i8;
    *(float4*)dst = u0;
    *(float4*)(dst + 4) = u1;
  }
}

// ---------------- merge the two key-segments ----------------
__global__ __launch_bounds__(256) void merge_kernel(const float* __restrict__ Opart,
                                                    const float2* __restrict__ ml2,
                                                    float* __restrict__ attno) {
  int blk = blockIdx.x;          // 686: bh*49 + qt
  int qt = blk % 49, bh = blk / 49;
  int b = bh / 7, h = bh % 7;
  int tid = threadIdx.x, q = tid & 63, dg = tid >> 6;
  size_t p0 = ((size_t)bh * 2 + 0) * 49 + qt;
  size_t p1 = ((size_t)bh * 2 + 1) * 49 + qt;
  float2 a = ml2[p0 * 64 + q];
  float2 c = ml2[p1 * 64 + q];
  float m = fmaxf(a.x, c.x);
  float w0 = exp2fast(a.x - m), w1 = exp2fast(c.x - m);
  float inv = 1.f / (a.y * w0 + c.y * w1);
  #pragma unroll
  for (int i = 0; i < 8; ++i) {
    int d = dg * 8 + i;
    float o = (Opart[p0 * 2048 + d * 64 + q] * w0 + Opart[p1 * 2048 + d * 64 + q] * w1) * inv;
    attno[((size_t)b * CCH + h * 32 + d) * NPIX + qt * 64 + q] = o;
  }
}

// ---------------- channel means -> wx = wo*sigmoid(mean); beff += wx*b3 ----------------
__global__ __launch_bounds__(256) void wx_kernel(const float* __restrict__ out,
                                                 const float* __restrict__ wo,
                                                 const float* __restrict__ b3,
                                                 float* __restrict__ wx,
                                                 float* __restrict__ beff) {
  __shared__ float scratch[8];
  int bc = blockIdx.x;
  int c = bc % CCH;
  int b = bc / CCH;
  const float* src = out + (size_t)bc * NPIX;
  float s = 0.f, dummy = 0.f;
  for (int i = threadIdx.x; i < NPIX; i += 256) s += src[i];
  blockReduce2(s, dummy, scratch);
  if (threadIdx.x == 0) {
    float mean = s * (1.f / (float)NPIX);
    float x1 = 1.f / (1.f + expf(-mean));
    float v = wo[c] * x1;
    wx[bc] = v;
    atomicAdd(&beff[b], v * b3[c]);
  }
}

// ---------------- weff[b][cp*9+k] = sum_c wx[b][c]*w3[c][cp*9+k] ----------------
__global__ void weff_kernel(const float* __restrict__ wx, const float* __restrict__ w3,
                            float* __restrict__ weff) {
  int t = blockIdx.x * 256 + threadIdx.x;
  if (t < 2 * 2016) {
    int b = t / 2016, rem = t - b * 2016;
    const float* wxb = wx + b * CCH;
    float a0 = 0.f, a1 = 0.f, a2 = 0.f, a3 = 0.f;
    for (int c = 0; c < CCH; c += 4) {
      a0 = fmaf(wxb[c + 0], w3[(size_t)(c + 0) * 2016 + rem], a0);
      a1 = fmaf(wxb[c + 1], w3[(size_t)(c + 1) * 2016 + rem], a1);
      a2 = fmaf(wxb[c + 2], w3[(size_t)(c + 2) * 2016 + rem], a2);
      a3 = fmaf(wxb[c + 3], w3[(size_t)(c + 3) * 2016 + rem], a3);
    }
    weff[t] = (a0 + a1) + (a2 + a3);
  }
}

// ---------------- M_k(px) = sum_cp weff[cp][k] * attno_cp(px)  (9 channel-collapsed maps) ----------------
__global__ __launch_bounds__(256) void mk_kernel(const float* __restrict__ attno,
                                                 const float* __restrict__ weff,
                                                 float* __restrict__ Mout) {
  __shared__ float wsh[2016];
  __shared__ float msh[4][9][64];
  int b = blockIdx.y, tile = blockIdx.x;
  int tid = threadIdx.x;
  for (int i = tid; i < 2016; i += 256) wsh[i] = weff[b * 2016 + i];
  __syncthreads();
  int p = tid & 63, s = tid >> 6;
  int px = tile * 64 + p;
  const float* A = attno + (size_t)b * CCH * NPIX + px;
  float m[9];
  #pragma unroll
  for (int k = 0; k < 9; ++k) m[k] = 0.f;
  for (int c = s * 56; c < s * 56 + 56; ++c) {
    float a = A[(size_t)c * NPIX];
    const float* wp = &wsh[c * 9];
    #pragma unroll
    for (int k = 0; k < 9; ++k) m[k] = fmaf(a, wp[k], m[k]);
  }
  #pragma unroll
  for (int k = 0; k < 9; ++k) msh[s][k][p] = m[k];
  __syncthreads();
  for (int i = tid; i < 576; i += 256) {
    int k = i >> 6, p2 = i & 63;
    float v = msh[0][k][p2] + msh[1][k][p2] + msh[2][k][p2] + msh[3][k][p2];
    Mout[((size_t)b * 9 + k) * NPIX + tile * 64 + p2] = v;
  }
}

// ---------------- final: out = sigmoid(sum_k M_k(shifted) + beff + bo) ----------------
__global__ void final_kernel(const float* __restrict__ Mout, const float* __restrict__ beff,
                             const float* __restrict__ bo, float* __restrict__ dout) {
  int px = blockIdx.x * 256 + threadIdx.x;
  int b = blockIdx.y;
  if (px >= NPIX) return;
  int y = px / 56, x = px - y * 56;
  const float* Mb = Mout + (size_t)b * 9 * NPIX;
  float s = 0.f;
  #pragma unroll
  for (int ky = 0; ky < 3; ++ky) {
    int yy = y + ky - 1;
    if (yy < 0 || yy >= 56) continue;
    #pragma unroll
    for (int kx = 0; kx < 3; ++kx) {
      int xx = x + kx - 1;
      if (xx < 0 || xx >= 56) continue;
      s += Mb[(ky * 3 + kx) * NPIX + yy * 56 + xx];
    }
  }
  float v = s + beff[b] + bo[0];
  dout[b * NPIX + px] = 1.f / (1.f + expf(-v));
}

extern "C" void kernel_launch(void* const* d_in, const int* in_sizes, int n_in,
                              void* d_out, int out_size, void* d_ws, size_t ws_size,
                              hipStream_t stream) {
  (void)in_sizes; (void)n_in; (void)out_size; (void)ws_size;
  const float* D = (const float*)d_in[0];
  const float* wq = (const float*)d_in[1];
  const float* bq = (const float*)d_in[2];
  const float* wk = (const float*)d_in[3];
  const float* bk = (const float*)d_in[4];
  const float* wv = (const float*)d_in[5];
  const float* bv = (const float*)d_in[6];
  const float* gn_w = (const float*)d_in[7];
  const float* gn_b = (const float*)d_in[8];
  const float* lambda_init = (const float*)d_in[9];
  const float* lq1 = (const float*)d_in[10];
  const float* lk1 = (const float*)d_in[11];
  const float* lq2 = (const float*)d_in[12];
  const float* lk2 = (const float*)d_in[13];
  const float* w3 = (const float*)d_in[14];
  const float* b3 = (const float*)d_in[15];
  const float* wo = (const float*)d_in[16];
  const float* bo = (const float*)d_in[17];

  char* p = (char*)d_ws;
  _Float16* Dh = (_Float16*)p;          p += 2809856;
  _Float16* senh_h = (_Float16*)p;      p += 2809856;
  _Float16* Whq = (_Float16*)p;         p += 200704;
  _Float16* Whk = (_Float16*)p;         p += 200704;
  _Float16* Whv = (_Float16*)p;         p += 100352;
  _Float16* Qt = (_Float16*)p;          p += 5619712;
  _Float16* Kt = (_Float16*)p;          p += 5619712;
  _Float16* Vt = (_Float16*)p;          p += 2809856;
  float* Opart = (float*)p;             p += 11239424;
  float2* ml2 = (float2*)p;             p += 702464;
  float* attno = (float*)p;             p += 5619712;
  float* Mout = (float*)p;              p += 225792;
  float* wx = (float*)p;                p += 1792;
  float* weff = (float*)p;              p += 16128;
  float* beff = (float*)p;              p += 64;
  float* lam = (float*)p;               p += 64;

  hipMemsetAsync(beff, 0, 2 * sizeof(float), stream);
  lam_kernel<<<1, 64, 0, stream>>>(lq1, lk1, lq2, lk2, lambda_init, lam);
  prep_kernel<<<448, 256, 0, stream>>>(D, gn_w, gn_b, senh_h, Dh);
  wcvt_kernel<<<245, 256, 0, stream>>>(wq, wk, wv, Whq, Whk, Whv);
  gemm_f16_kernel<<<dim3(49, 7, 2), 256, 0, stream>>>(Whq, senh_h, bq, Qt, 448, 1, lam);
  gemm_f16_kernel<<<dim3(49, 7, 2), 256, 0, stream>>>(Whk, Dh, bk, Kt, 448, 2, nullptr);
  gemm_f16_kernel<<<dim3(49, 4, 2), 256, 0, stream>>>(Whv, Dh, bv, Vt, 224, 0, nullptr);
  attn_part_kernel<<<1372, 256, 0, stream>>>(Qt, Kt, Vt, Opart, ml2);
  merge_kernel<<<686, 256, 0, stream>>>(Opart, ml2, attno);
  wx_kernel<<<448, 256, 0, stream>>>(attno, wo, b3, wx, beff);
  weff_kernel<<<16, 256, 0, stream>>>(wx, w3, weff);
  mk_kernel<<<dim3(49, 2), 256, 0, stream>>>(attno, weff, Mout);
  final_kernel<<<dim3(13, 2), 256, 0, stream>>>(Mout, beff, bo, (float*)d_out);
}

// Round 7
// 232.095 us; speedup vs baseline: 4.3681x; 1.0284x over previous
//
#include <hip/hip_runtime.h>
#include <math.h>

#define NPIX 3136   // 56*56
#define CCH  224
#define SCALING 0.17677669529663687f   // 32^-0.5
#define LOG2E 1.4426950408889634f
#define SCL2 (SCALING * LOG2E)         // folded into Q: logits in log2 domain

typedef _Float16 half8_t __attribute__((ext_vector_type(8)));
typedef _Float16 half4_t __attribute__((ext_vector_type(4)));
typedef _Float16 half2_t __attribute__((ext_vector_type(2)));
typedef float floatx4 __attribute__((ext_vector_type(4)));

__device__ __forceinline__ float exp2fast(float x) { return __builtin_amdgcn_exp2f(x); }

// ---------------- helpers ----------------
__device__ __forceinline__ void blockReduce2(float& a, float& b, float* scratch) {
  #pragma unroll
  for (int off = 32; off > 0; off >>= 1) {
    a += __shfl_down(a, off);
    b += __shfl_down(b, off);
  }
  int wid = threadIdx.x >> 6, lane = threadIdx.x & 63;
  if (lane == 0) { scratch[wid * 2] = a; scratch[wid * 2 + 1] = b; }
  __syncthreads();
  if (threadIdx.x == 0) {
    float sa = 0.f, sb = 0.f;
    #pragma unroll
    for (int i = 0; i < 4; ++i) { sa += scratch[2 * i]; sb += scratch[2 * i + 1]; }
    scratch[0] = sa; scratch[1] = sb;
  }
  __syncthreads();
  a = scratch[0]; b = scratch[1];
}

// ---------------- lam ----------------
__global__ void lam_kernel(const float* __restrict__ lq1, const float* __restrict__ lk1,
                           const float* __restrict__ lq2, const float* __restrict__ lk2,
                           const float* __restrict__ lambda_init, float* __restrict__ lam) {
  int t = threadIdx.x;
  float p1 = (t < 32) ? lq1[t] * lk1[t] : 0.f;
  float p2 = (t < 32) ? lq2[t] * lk2[t] : 0.f;
  #pragma unroll
  for (int off = 16; off > 0; off >>= 1) {
    p1 += __shfl_down(p1, off);
    p2 += __shfl_down(p2, off);
  }
  if (t == 0) {
    float d = expf(p1) - expf(p2);
    d = fminf(fmaxf(d, 0.f), 1.f);
    lam[0] = d + lambda_init[0];
  }
}

// ---------------- prep: gating + per-channel instance norm; emits f16 senh and f16 D ----------------
__global__ __launch_bounds__(256) void prep_kernel(const float* __restrict__ D,
                                                   const float* __restrict__ gn_w,
                                                   const float* __restrict__ gn_b,
                                                   _Float16* __restrict__ senh_h,
                                                   _Float16* __restrict__ Dh) {
  __shared__ float img[NPIX];
  __shared__ float xh[56];
  __shared__ float xw[56];
  __shared__ float rp[56][4];
  __shared__ float cp_[56][4];
  __shared__ float scratch[8];
  int bc = blockIdx.x;
  int c = bc % CCH;
  const float* src = D + (size_t)bc * NPIX;
  float4* img4 = (float4*)img;
  const float4* src4 = (const float4*)src;
  half4_t* dh4 = (half4_t*)(Dh + (size_t)bc * NPIX);
  for (int i = threadIdx.x; i < NPIX / 4; i += 256) {
    float4 v = src4[i];
    img4[i] = v;
    half4_t hv;
    hv[0] = (_Float16)v.x; hv[1] = (_Float16)v.y;
    hv[2] = (_Float16)v.z; hv[3] = (_Float16)v.w;
    dh4[i] = hv;
  }
  __syncthreads();
  int t = threadIdx.x;
  if (t < 224) {            // row partial sums: 4 threads per row, 14 elems each
    int r = t >> 2, qq = t & 3;
    float s = 0.f;
    #pragma unroll 14
    for (int j = 0; j < 14; ++j) s += img[r * 56 + qq * 14 + j];
    rp[r][qq] = s;
  }
  __syncthreads();
  if (t < 224) {            // col partial sums
    int cc = t >> 2, qq = t & 3;
    float s = 0.f;
    #pragma unroll 14
    for (int j = 0; j < 14; ++j) s += img[(qq * 14 + j) * 56 + cc];
    cp_[cc][qq] = s;
  }
  __syncthreads();
  if (t < 56) xh[t] = (rp[t][0] + rp[t][1] + rp[t][2] + rp[t][3]) * (1.f / 56.f);
  else if (t >= 64 && t < 120) {
    int cc = t - 64;
    xw[cc] = (cp_[cc][0] + cp_[cc][1] + cp_[cc][2] + cp_[cc][3]) * (1.f / 56.f);
  }
  __syncthreads();
  float sum = 0.f, ssq = 0.f;
  for (int i = threadIdx.x; i < NPIX; i += 256) {
    int y = i / 56, x = i - y * 56;
    float d = img[i];
    float tt = xh[y] + xw[x];
    float sg = 1.f / (1.f + __expf(-tt));
    float g = d * sg;
    img[i] = g;
    sum += g;
    ssq += g * g;
  }
  blockReduce2(sum, ssq, scratch);
  float mu = sum * (1.f / (float)NPIX);
  float var = ssq * (1.f / (float)NPIX) - mu * mu;
  float rstd = rsqrtf(var + 1e-5f);
  float a = gn_w[c] * rstd;
  float bb = gn_b[c] - mu * a;
  _Float16* dst = senh_h + (size_t)bc * NPIX;
  for (int i = threadIdx.x; i < NPIX; i += 256) dst[i] = (_Float16)fmaf(img[i], a, bb);
}

// ---------------- convert conv weights to f16 once ----------------
__global__ void wcvt_kernel(const float* __restrict__ wq, const float* __restrict__ wk,
                            const float* __restrict__ wv,
                            _Float16* __restrict__ whq, _Float16* __restrict__ whk,
                            _Float16* __restrict__ whv) {
  int i = blockIdx.x * 256 + threadIdx.x;   // float4 index
  const int NQ = 448 * 224 / 4;
  const int NV = 224 * 224 / 4;
  const float* src; _Float16* dst; int off;
  if (i < NQ) { src = wq; dst = whq; off = i; }
  else if (i < 2 * NQ) { src = wk; dst = whk; off = i - NQ; }
  else if (i < 2 * NQ + NV) { src = wv; dst = whv; off = i - 2 * NQ; }
  else return;
  float4 v = ((const float4*)src)[off];
  half4_t h;
  h[0] = (_Float16)v.x; h[1] = (_Float16)v.y;
  h[2] = (_Float16)v.z; h[3] = (_Float16)v.w;
  ((half4_t*)dst)[off] = h;
}

// ---------------- fused QKV f16 MFMA GEMM ----------------
// blockIdx.y = sel: 0..6 Q row-tiles, 7..13 K row-tiles, 14..17 V row-tiles. z = batch.
__global__ __launch_bounds__(256) void gemm_qkv_kernel(const _Float16* __restrict__ Whq,
                                                       const _Float16* __restrict__ Whk,
                                                       const _Float16* __restrict__ Whv,
                                                       const _Float16* __restrict__ senh_h,
                                                       const _Float16* __restrict__ Dh,
                                                       const float* __restrict__ bq,
                                                       const float* __restrict__ bk,
                                                       const float* __restrict__ bv,
                                                       _Float16* __restrict__ Qt,
                                                       _Float16* __restrict__ Kt,
                                                       _Float16* __restrict__ Vt,
                                                       const float* __restrict__ lamp) {
  __shared__ _Float16 Xs[2][64][40];   // n-major, pad 40 (rows 80B)
  __shared__ _Float16 Cs[64][72];
  int b = blockIdx.z;
  int sel = blockIdx.y;
  int mode, r0, M;
  const _Float16* Wh;
  const _Float16* Xb;
  const float* bias;
  _Float16* Y;
  if (sel < 7)       { mode = 1; r0 = sel * 64;        M = 448; Wh = Whq; Xb = senh_h; bias = bq; Y = Qt; }
  else if (sel < 14) { mode = 2; r0 = (sel - 7) * 64;  M = 448; Wh = Whk; Xb = Dh;     bias = bk; Y = Kt; }
  else               { mode = 0; r0 = (sel - 14) * 64; M = 224; Wh = Whv; Xb = Dh;     bias = bv; Y = Vt; }
  Xb += (size_t)b * CCH * NPIX;
  int n0 = blockIdx.x * 64;
  int tid = threadIdx.x;
  int w = tid >> 6, lane = tid & 63, q = lane & 15, g = lane >> 4;

  int wrow = r0 + w * 16 + q;
  if (wrow >= M) wrow = M - 1;               // guarded at epilogue
  half8_t wfrag[7];
  #pragma unroll
  for (int kc = 0; kc < 7; ++kc)
    wfrag[kc] = *(const half8_t*)&Wh[(size_t)wrow * 224 + kc * 32 + g * 8];

  floatx4 acc[4];
  #pragma unroll
  for (int t = 0; t < 4; ++t)
    #pragma unroll
    for (int r = 0; r < 4; ++r) acc[t][r] = 0.f;

  int cp = tid & 15, ng = tid >> 4;   // staging: 2 channels x 4 pixels
  // prologue: stage kc=0 into buf 0
  {
    const _Float16* x0 = Xb + (size_t)(2 * cp) * NPIX + n0 + ng * 4;
    half4_t xa = *(const half4_t*)x0;
    half4_t xb = *(const half4_t*)(x0 + NPIX);
    #pragma unroll
    for (int j = 0; j < 4; ++j) {
      half2_t hw; hw[0] = xa[j]; hw[1] = xb[j];
      *(half2_t*)&Xs[0][ng * 4 + j][2 * cp] = hw;
    }
  }
  __syncthreads();
  #pragma unroll
  for (int kc = 0; kc < 7; ++kc) {
    int cur = kc & 1;
    half4_t xa, xb;
    if (kc < 6) {
      const _Float16* x0 = Xb + (size_t)((kc + 1) * 32 + 2 * cp) * NPIX + n0 + ng * 4;
      xa = *(const half4_t*)x0;
      xb = *(const half4_t*)(x0 + NPIX);
    }
    #pragma unroll
    for (int t = 0; t < 4; ++t) {
      half8_t xfrag = *(const half8_t*)&Xs[cur][16 * t + q][g * 8];
      acc[t] = __builtin_amdgcn_mfma_f32_16x16x32_f16(wfrag[kc], xfrag, acc[t], 0, 0, 0);
    }
    if (kc < 6) {
      #pragma unroll
      for (int j = 0; j < 4; ++j) {
        half2_t hw; hw[0] = xa[j]; hw[1] = xb[j];
        *(half2_t*)&Xs[cur ^ 1][ng * 4 + j][2 * cp] = hw;
      }
    }
    __syncthreads();
  }

  float lamv = (mode == 1) ? lamp[0] : 0.f;
  #pragma unroll
  for (int t = 0; t < 4; ++t) {
    #pragma unroll
    for (int r = 0; r < 4; ++r) {
      int m = w * 16 + 4 * g + r;
      int n = 16 * t + q;
      int gm = r0 + m;
      float v = 0.f;
      if (gm < M) {
        v = acc[t][r] + bias[gm];
        if (mode == 1) v *= (gm < CCH) ? SCL2 : (-lamv * SCL2);
      }
      Cs[m][n] = (_Float16)v;
    }
  }
  __syncthreads();

  if (mode == 0) {
    int row = tid >> 2, oct = tid & 3;
    if (r0 + row < M) {
      half8_t u0 = *(half8_t*)&Cs[row][oct * 16];
      half8_t u1 = *(half8_t*)&Cs[row][oct * 16 + 8];
      _Float16* dst = Y + ((size_t)b * CCH + r0 + row) * NPIX + n0 + oct * 16;
      *(half8_t*)dst = u0;
      *(half8_t*)(dst + 8) = u1;
    }
  } else {
    int n = tid & 63, quarter = tid >> 6;
    int vbase = r0 + quarter * 16;
    int chunk = vbase >= CCH;
    int ch_in = vbase - chunk * CCH;
    int hh = ch_in >> 5;
    int dstart = chunk * 32 + (ch_in & 31);
    _Float16 tmp[16];
    #pragma unroll
    for (int i = 0; i < 16; ++i) tmp[i] = Cs[quarter * 16 + i][n];
    _Float16* dst = Y + (((size_t)b * 7 + hh) * NPIX + (n0 + n)) * 64 + dstart;
    *(half8_t*)dst = *(half8_t*)&tmp[0];
    *(half8_t*)(dst + 8) = *(half8_t*)&tmp[8];
  }
}

// ---------------- MFMA flash attention, split-K x4 + exp2 + defer-max ----------------
// grid 2744 = 14 bh * 4 seg * 49 qt. Partials f16 (un-normalized) + (m,l) f32.
__global__ __launch_bounds__(256) void attn_part_kernel(const _Float16* __restrict__ Qt,
                                                        const _Float16* __restrict__ Kt,
                                                        const _Float16* __restrict__ Vt,
                                                        _Float16* __restrict__ Opart,
                                                        float2* __restrict__ ml2) {
  __shared__ _Float16 K_lds[2][64][72];
  __shared__ _Float16 V_lds[2][32][72];
  __shared__ _Float16 P_lds[64][72];

  // XCD swizzle: 2744 = 8 * 343 exactly
  int orig = blockIdx.x;
  int wg = (orig & 7) * 343 + (orig >> 3);
  int qt = wg % 49;
  int rest = wg / 49;            // 0..55
  int seg = rest & 3, bh = rest >> 2;
  int h = bh % 7, b = bh / 7;
  int t0 = (seg == 0) ? 0 : (12 * seg + 1);
  int nt = seg ? 12 : 13;

  int tid = threadIdx.x;
  int w = tid >> 6, lane = tid & 63;
  int q = lane & 15, g = lane >> 4;
  int nq = qt * 64 + w * 16 + q;

  const _Float16* Qb = Qt + ((size_t)(b * 7 + h) * NPIX + nq) * 64;
  const _Float16* Kb = Kt + (size_t)(b * 7 + h) * NPIX * 64;
  const _Float16* Vb = Vt + ((size_t)b * CCH + h * 32) * NPIX;

  half8_t qv[2];
  qv[0] = *(const half8_t*)(Qb + g * 8);
  qv[1] = *(const half8_t*)(Qb + 32 + g * 8);

  floatx4 oacc[2];
  #pragma unroll
  for (int dt = 0; dt < 2; ++dt)
    #pragma unroll
    for (int r = 0; r < 4; ++r) oacc[dt][r] = 0.f;
  float mrun = -INFINITY, lrun = 0.f;

  int kkey = tid >> 2, koct = (tid & 3) * 16;
  const _Float16* ksrc = Kb + ((size_t)t0 * 64 + kkey) * 64 + koct;
  int vd = tid >> 3, voff = (tid & 7) * 8;
  const _Float16* vsrc = Vb + (size_t)vd * NPIX + t0 * 64 + voff;

  half8_t kr0, kr1, vr;
  kr0 = *(const half8_t*)(ksrc);
  kr1 = *(const half8_t*)(ksrc + 8);
  vr = *(const half8_t*)(vsrc);
  *(half8_t*)&K_lds[0][kkey][koct] = kr0;
  *(half8_t*)&K_lds[0][kkey][koct + 8] = kr1;
  *(half8_t*)&V_lds[0][vd][voff] = vr;
  __syncthreads();

  for (int kc = 0; kc < nt; ++kc) {
    int cur = kc & 1;
    if (kc < nt - 1) {
      size_t m0 = (size_t)(kc + 1) * 64;
      kr0 = *(const half8_t*)(ksrc + m0 * 64);
      kr1 = *(const half8_t*)(ksrc + m0 * 64 + 8);
      vr = *(const half8_t*)(vsrc + m0);
    }

    // ---- QK^T (log2-domain logits) ----
    floatx4 sacc[4];
    #pragma unroll
    for (int t = 0; t < 4; ++t)
      #pragma unroll
      for (int r = 0; r < 4; ++r) sacc[t][r] = 0.f;
    #pragma unroll
    for (int t = 0; t < 4; ++t) {
      #pragma unroll
      for (int c = 0; c < 2; ++c) {
        half8_t ka = *(const half8_t*)&K_lds[cur][t * 16 + q][c * 32 + g * 8];
        sacc[t] = __builtin_amdgcn_mfma_f32_16x16x32_f16(ka, qv[c], sacc[t], 0, 0, 0);
      }
    }

    // ---- online softmax, defer-max (THR=8 in log2 units) ----
    float tmax = fmaxf(fmaxf(sacc[0][0], sacc[0][1]), fmaxf(sacc[0][2], sacc[0][3]));
    #pragma unroll
    for (int t = 1; t < 4; ++t)
      tmax = fmaxf(tmax, fmaxf(fmaxf(sacc[t][0], sacc[t][1]), fmaxf(sacc[t][2], sacc[t][3])));
    tmax = fmaxf(tmax, __shfl_xor(tmax, 16));
    tmax = fmaxf(tmax, __shfl_xor(tmax, 32));
    if (__any(tmax > mrun + 8.f)) {
      float mnew = fmaxf(mrun, tmax);
      float corr = exp2fast(mrun - mnew);
      lrun *= corr;
      #pragma unroll
      for (int dt = 0; dt < 2; ++dt)
        #pragma unroll
        for (int r = 0; r < 4; ++r) oacc[dt][r] *= corr;
      mrun = mnew;
    }
    float lsum = 0.f;
    #pragma unroll
    for (int t = 0; t < 4; ++t)
      #pragma unroll
      for (int r = 0; r < 4; ++r) {
        float p = exp2fast(sacc[t][r] - mrun);
        sacc[t][r] = p;
        lsum += p;
      }
    lsum += __shfl_xor(lsum, 16);
    lsum += __shfl_xor(lsum, 32);
    lrun += lsum;

    // ---- P -> f16 -> per-wave LDS rows ----
    #pragma unroll
    for (int t = 0; t < 4; ++t) {
      half4_t ph;
      ph[0] = (_Float16)sacc[t][0];
      ph[1] = (_Float16)sacc[t][1];
      ph[2] = (_Float16)sacc[t][2];
      ph[3] = (_Float16)sacc[t][3];
      *(half4_t*)&P_lds[w * 16 + q][t * 16 + g * 4] = ph;
    }

    // ---- PV ----
    #pragma unroll
    for (int dt = 0; dt < 2; ++dt) {
      #pragma unroll
      for (int c = 0; c < 2; ++c) {
        half8_t va = *(const half8_t*)&V_lds[cur][dt * 16 + q][c * 32 + g * 8];
        half8_t pb = *(const half8_t*)&P_lds[w * 16 + q][c * 32 + g * 8];
        oacc[dt] = __builtin_amdgcn_mfma_f32_16x16x32_f16(va, pb, oacc[dt], 0, 0, 0);
      }
    }

    if (kc < nt - 1) {
      *(half8_t*)&K_lds[cur ^ 1][kkey][koct] = kr0;
      *(half8_t*)&K_lds[cur ^ 1][kkey][koct + 8] = kr1;
      *(half8_t*)&V_lds[cur ^ 1][vd][voff] = vr;
    }
    __syncthreads();
  }

  // ---- write partials: transpose via LDS, coalesced f16 ----
  size_t pbase = (((size_t)bh * 4 + seg) * 49 + qt);
  float* out_lds = (float*)&K_lds[0][0][0];   // 32*68*4 = 8704B
  #pragma unroll
  for (int dt = 0; dt < 2; ++dt)
    #pragma unroll
    for (int r = 0; r < 4; ++r) {
      int d = dt * 16 + g * 4 + r;
      out_lds[d * 68 + w * 16 + q] = oacc[dt][r];
    }
  if (lane < 16) ml2[pbase * 64 + w * 16 + lane] = make_float2(mrun, lrun);
  __syncthreads();
  {
    int d = tid >> 3;
    int i8 = (tid & 7) << 3;
    half8_t hv;
    #pragma unroll
    for (int j = 0; j < 8; ++j) hv[j] = (_Float16)out_lds[d * 68 + i8 + j];
    *(half8_t*)(Opart + pbase * 2048 + d * 64 + i8) = hv;
  }
}

// ---------------- merge 4 key-segments; fused per-channel spatial sums ----------------
__global__ __launch_bounds__(256) void merge_kernel(const _Float16* __restrict__ Opart,
                                                    const float2* __restrict__ ml2,
                                                    float* __restrict__ attno,
                                                    float* __restrict__ wx_raw) {
  int blk = blockIdx.x;          // 686: bh*49 + qt
  int qt = blk % 49, bh = blk / 49;
  int b = bh / 7, h = bh % 7;
  int tid = threadIdx.x, q = tid & 63, dg = tid >> 6;
  size_t p0 = (size_t)bh * 4 * 49 + qt;
  float2 s0 = ml2[(p0 + 0 * 49) * 64 + q];
  float2 s1 = ml2[(p0 + 1 * 49) * 64 + q];
  float2 s2 = ml2[(p0 + 2 * 49) * 64 + q];
  float2 s3 = ml2[(p0 + 3 * 49) * 64 + q];
  float m = fmaxf(fmaxf(s0.x, s1.x), fmaxf(s2.x, s3.x));
  float w0 = exp2fast(s0.x - m), w1 = exp2fast(s1.x - m);
  float w2 = exp2fast(s2.x - m), w3 = exp2fast(s3.x - m);
  float inv = 1.f / (s0.y * w0 + s1.y * w1 + s2.y * w2 + s3.y * w3);
  float osum[8];
  #pragma unroll
  for (int i = 0; i < 8; ++i) {
    int d = dg * 8 + i;
    float o = ((float)Opart[(p0 + 0 * 49) * 2048 + d * 64 + q] * w0 +
               (float)Opart[(p0 + 1 * 49) * 2048 + d * 64 + q] * w1 +
               (float)Opart[(p0 + 2 * 49) * 2048 + d * 64 + q] * w2 +
               (float)Opart[(p0 + 3 * 49) * 2048 + d * 64 + q] * w3) * inv;
    attno[((size_t)b * CCH + h * 32 + d) * NPIX + qt * 64 + q] = o;
    osum[i] = o;
  }
  // per-wave butterfly: sum over the 64 pixels for each of this wave's 8 channels
  #pragma unroll
  for (int i = 0; i < 8; ++i) {
    #pragma unroll
    for (int off = 32; off > 0; off >>= 1) osum[i] += __shfl_xor(osum[i], off);
  }
  if ((tid & 63) == 0) {
    #pragma unroll
    for (int i = 0; i < 8; ++i)
      atomicAdd(&wx_raw[b * CCH + h * 32 + dg * 8 + i], osum[i]);
  }
}

// ---------------- weff: wx = wo*sigmoid(mean); weff = wx . w3; beff = wx.b3 + bo ----------------
__global__ __launch_bounds__(256) void weff_kernel(const float* __restrict__ wx_raw,
                                                   const float* __restrict__ wo,
                                                   const float* __restrict__ w3,
                                                   const float* __restrict__ b3,
                                                   const float* __restrict__ bo,
                                                   float* __restrict__ weff,
                                                   float* __restrict__ beff) {
  __shared__ float wsh[CCH];
  __shared__ float scratch[8];
  int b = blockIdx.y;
  int t = threadIdx.x;
  if (t < CCH) {
    float mean = wx_raw[b * CCH + t] * (1.f / (float)NPIX);
    wsh[t] = wo[t] / (1.f + expf(-mean));
  }
  __syncthreads();
  int rem = blockIdx.x * 252 + t;
  if (t < 252 && rem < 2016) {
    float a0 = 0.f, a1 = 0.f, a2 = 0.f, a3 = 0.f;
    for (int c = 0; c < CCH; c += 4) {
      a0 = fmaf(wsh[c + 0], w3[(size_t)(c + 0) * 2016 + rem], a0);
      a1 = fmaf(wsh[c + 1], w3[(size_t)(c + 1) * 2016 + rem], a1);
      a2 = fmaf(wsh[c + 2], w3[(size_t)(c + 2) * 2016 + rem], a2);
      a3 = fmaf(wsh[c + 3], w3[(size_t)(c + 3) * 2016 + rem], a3);
    }
    weff[b * 2016 + rem] = (a0 + a1) + (a2 + a3);
  }
  if (blockIdx.x == 0) {
    float p = (t < CCH) ? wsh[t] * b3[t] : 0.f;
    float dummy = 0.f;
    blockReduce2(p, dummy, scratch);
    if (t == 0) beff[b] = p + bo[0];
  }
}

// ---------------- M_k(px) = sum_cp weff[cp][k] * attno_cp(px) ----------------
__global__ __launch_bounds__(256) void mk_kernel(const float* __restrict__ attno,
                                                 const float* __restrict__ weff,
                                                 float* __restrict__ Mout) {
  __shared__ float wsh[2016];
  __shared__ float msh[4][9][64];
  int b = blockIdx.y, tile = blockIdx.x;
  int tid = threadIdx.x;
  for (int i = tid; i < 2016; i += 256) wsh[i] = weff[b * 2016 + i];
  __syncthreads();
  int p = tid & 63, s = tid >> 6;
  int px = tile * 64 + p;
  const float* A = attno + (size_t)b * CCH * NPIX + px;
  float m[9];
  #pragma unroll
  for (int k = 0; k < 9; ++k) m[k] = 0.f;
  for (int c = s * 56; c < s * 56 + 56; ++c) {
    float a = A[(size_t)c * NPIX];
    const float* wp = &wsh[c * 9];
    #pragma unroll
    for (int k = 0; k < 9; ++k) m[k] = fmaf(a, wp[k], m[k]);
  }
  #pragma unroll
  for (int k = 0; k < 9; ++k) msh[s][k][p] = m[k];
  __syncthreads();
  for (int i = tid; i < 576; i += 256) {
    int k = i >> 6, p2 = i & 63;
    float v = msh[0][k][p2] + msh[1][k][p2] + msh[2][k][p2] + msh[3][k][p2];
    Mout[((size_t)b * 9 + k) * NPIX + tile * 64 + p2] = v;
  }
}

// ---------------- final: out = sigmoid(sum_k M_k(shifted) + beff) ----------------
__global__ void final_kernel(const float* __restrict__ Mout, const float* __restrict__ beff,
                             float* __restrict__ dout) {
  int px = blockIdx.x * 256 + threadIdx.x;
  int b = blockIdx.y;
  if (px >= NPIX) return;
  int y = px / 56, x = px - y * 56;
  const float* Mb = Mout + (size_t)b * 9 * NPIX;
  float s = 0.f;
  #pragma unroll
  for (int ky = 0; ky < 3; ++ky) {
    int yy = y + ky - 1;
    if (yy < 0 || yy >= 56) continue;
    #pragma unroll
    for (int kx = 0; kx < 3; ++kx) {
      int xx = x + kx - 1;
      if (xx < 0 || xx >= 56) continue;
      s += Mb[(ky * 3 + kx) * NPIX + yy * 56 + xx];
    }
  }
  float v = s + beff[b];
  dout[b * NPIX + px] = 1.f / (1.f + expf(-v));
}

extern "C" void kernel_launch(void* const* d_in, const int* in_sizes, int n_in,
                              void* d_out, int out_size, void* d_ws, size_t ws_size,
                              hipStream_t stream) {
  (void)in_sizes; (void)n_in; (void)out_size; (void)ws_size;
  const float* D = (const float*)d_in[0];
  const float* wq = (const float*)d_in[1];
  const float* bq = (const float*)d_in[2];
  const float* wk = (const float*)d_in[3];
  const float* bk = (const float*)d_in[4];
  const float* wv = (const float*)d_in[5];
  const float* bv = (const float*)d_in[6];
  const float* gn_w = (const float*)d_in[7];
  const float* gn_b = (const float*)d_in[8];
  const float* lambda_init = (const float*)d_in[9];
  const float* lq1 = (const float*)d_in[10];
  const float* lk1 = (const float*)d_in[11];
  const float* lq2 = (const float*)d_in[12];
  const float* lk2 = (const float*)d_in[13];
  const float* w3 = (const float*)d_in[14];
  const float* b3 = (const float*)d_in[15];
  const float* wo = (const float*)d_in[16];
  const float* bo = (const float*)d_in[17];

  char* p = (char*)d_ws;
  _Float16* Dh = (_Float16*)p;          p += 2809856;
  _Float16* senh_h = (_Float16*)p;      p += 2809856;
  _Float16* Whq = (_Float16*)p;         p += 200704;
  _Float16* Whk = (_Float16*)p;         p += 200704;
  _Float16* Whv = (_Float16*)p;         p += 100352;
  _Float16* Qt = (_Float16*)p;          p += 5619712;
  _Float16* Kt = (_Float16*)p;          p += 5619712;
  _Float16* Vt = (_Float16*)p;          p += 2809856;
  _Float16* Opart = (_Float16*)p;       p += 11239424;   // 14*4*49*2048*2
  float2* ml2 = (float2*)p;             p += 1404928;    // 14*4*49*64*8
  float* attno = (float*)p;             p += 5619712;
  float* Mout = (float*)p;              p += 225792;
  float* wx_raw = (float*)p;            p += 1792;
  float* beff = (float*)p;              p += 64;
  float* lam = (float*)p;               p += 64;
  float* weff = (float*)p;              p += 16128;

  hipMemsetAsync(wx_raw, 0, 1792 + 64, stream);   // wx_raw + beff
  lam_kernel<<<1, 64, 0, stream>>>(lq1, lk1, lq2, lk2, lambda_init, lam);
  prep_kernel<<<448, 256, 0, stream>>>(D, gn_w, gn_b, senh_h, Dh);
  wcvt_kernel<<<245, 256, 0, stream>>>(wq, wk, wv, Whq, Whk, Whv);
  gemm_qkv_kernel<<<dim3(49, 18, 2), 256, 0, stream>>>(Whq, Whk, Whv, senh_h, Dh,
                                                       bq, bk, bv, Qt, Kt, Vt, lam);
  attn_part_kernel<<<2744, 256, 0, stream>>>(Qt, Kt, Vt, Opart, ml2);
  merge_kernel<<<686, 256, 0, stream>>>(Opart, ml2, attno, wx_raw);
  weff_kernel<<<dim3(8, 2), 256, 0, stream>>>(wx_raw, wo, w3, b3, bo, weff, beff);
  mk_kernel<<<dim3(49, 2), 256, 0, stream>>>(attno, weff, Mout);
  final_kernel<<<dim3(13, 2), 256, 0, stream>>>(Mout, beff, (float*)d_out);
}